// Round 7
// baseline (573.618 us; speedup 1.0000x reference)
//
#include <hip/hip_runtime.h>
#include <hip/hip_bf16.h>
#include <math.h>

#define N_ATOMS 500000
#define EPS 1e-5f
#define LDA 296   // bf16 elems per A row: 288 + 8 pad (breaks bank aliasing)

// blocks per degree segment (2048 blocks = 8 blocks/CU on 256 CUs),
// proportional to gather volume n_d*(d+1) -> equal gather work per block
#define NB1 111
#define NB2 498
#define NB3 886
#define NB4 553
#define NBLK 2048

#define SEG_ELEMS 36864   // 288*128 bf16 per packed weight segment

typedef __attribute__((ext_vector_type(8))) short short8;
typedef __attribute__((ext_vector_type(4))) float floatx4;

__device__ __forceinline__ unsigned short f2bf(float f) {
    unsigned int x = __float_as_uint(f);
    x += 0x7FFF + ((x >> 16) & 1);          // round-to-nearest-even
    return (unsigned short)(x >> 16);
}

__device__ __forceinline__ float4 add4(float4 a, float4 b) {
    return make_float4(a.x + b.x, a.y + b.y, a.z + b.z, a.w + b.w);
}

__device__ __forceinline__ void st_bf4(unsigned short* p, float4 v) {
    ushort4 u;
    u.x = f2bf(v.x); u.y = f2bf(v.y); u.z = f2bf(v.z); u.w = f2bf(v.w);
    *reinterpret_cast<ushort4*>(p) = u;     // ds_write_b64
}

// ---------------------------------------------------------------------------
// Pack weights into MFMA B-fragment layout, bf16.
// packed[d]: (ks 0..8, ntg 0..7, lane 0..63) -> short8; col = ntg*16+(lane&15),
// k = ks*32 + (lane>>4)*8 + j; k<144 -> W_d rows, k<272 -> W_self, else 0.
// ---------------------------------------------------------------------------
__global__ __launch_bounds__(256) void gdc_pack(
    const float* __restrict__ W1, const float* __restrict__ W2,
    const float* __restrict__ W3, const float* __restrict__ W4,
    const float* __restrict__ Wself, unsigned short* __restrict__ packed)
{
    const int t = blockIdx.x * 256 + threadIdx.x;
    if (t >= 4 * 9 * 8 * 64) return;
    const int d    = t / 4608;
    const int r    = t % 4608;
    const int ks   = r / 512;
    const int nt   = (r % 512) / 64;
    const int lane = r % 64;
    const float* Wd = (d == 0) ? W1 : (d == 1) ? W2 : (d == 2) ? W3 : W4;
    const int col = nt * 16 + (lane & 15);
    short8 v;
    #pragma unroll
    for (int j = 0; j < 8; ++j) {
        const int k = ks * 32 + ((lane >> 4) << 3) + j;
        float w = 0.f;
        if (k < 144)      w = Wd[k * 128 + col];
        else if (k < 272) w = Wself[(k - 144) * 128 + col];
        v[j] = (short)f2bf(w);
    }
    *reinterpret_cast<short8*>(packed + (size_t)d * SEG_ELEMS
                               + ((size_t)(ks * 8 + nt) * 64 + lane) * 8) = v;
}

// ---------------------------------------------------------------------------
// Block loop: 4 waves share one 32-row A tile. Wave wv owns cols [32wv,32wv+32).
// A K-layout: [a_sum 0..127 | b_sum 128..143 | self 144..271 | pad 272..287].
// ---------------------------------------------------------------------------
template <int DEG>
__device__ __forceinline__ void block_loop(
    const float* __restrict__ atom, const float* __restrict__ bond,
    const int* __restrict__ aidx, const int* __restrict__ bidx,
    const unsigned short* __restrict__ pw,
    float* __restrict__ out,
    unsigned short* __restrict__ A, int* __restrict__ own_lds,
    int n, int lb, int nb, int tid, int lane, int wv)
{
    const int m   = tid >> 3;            // node row 0..31 (block-wide gather)
    const int q8  = tid & 7;             // k-slice 0..7 (16 floats each)
    const int ccol = lane & 15;          // C col within 16-tile / A frag row
    const int crow = lane >> 4;          // C row group 0..3
    const int nbase = wv * 32;

    float psum[2] = {0.f, 0.f}, psq[2] = {0.f, 0.f};

    const int tiles = (n + 31) >> 5;

    for (int t = lb; t < tiles; t += nb) {
        const int i0 = t << 5;
        const int i = i0 + m;

        // ---- gather: 32 nodes x 8 slices across 256 threads ----
        if (i < n) {
            const int* ar = aidx + (size_t)i * (DEG + 1);
            const int own = ar[0];
            if (q8 == 0) own_lds[m] = own;
            const float4* s = (const float4*)(atom + (size_t)own * 128 + q8 * 16);
            float4 a0 = s[0], a1 = s[1], a2 = s[2], a3 = s[3];
            unsigned short* rowp = A + m * LDA;
            // self slice -> cols 144 + q8*16
            st_bf4(rowp + 144 + q8 * 16 + 0,  a0);
            st_bf4(rowp + 144 + q8 * 16 + 4,  a1);
            st_bf4(rowp + 144 + q8 * 16 + 8,  a2);
            st_bf4(rowp + 144 + q8 * 16 + 12, a3);
            #pragma unroll
            for (int j = 1; j <= DEG; ++j) {
                const float4* p = (const float4*)(atom + (size_t)ar[j] * 128 + q8 * 16);
                a0 = add4(a0, p[0]); a1 = add4(a1, p[1]);
                a2 = add4(a2, p[2]); a3 = add4(a3, p[3]);
            }
            st_bf4(rowp + q8 * 16 + 0,  a0);
            st_bf4(rowp + q8 * 16 + 4,  a1);
            st_bf4(rowp + q8 * 16 + 8,  a2);
            st_bf4(rowp + q8 * 16 + 12, a3);
            // bonds: this thread covers 2 of 16 cols
            {
                const int* br = bidx + (size_t)i * DEG;
                float bx = 0.f, by = 0.f;
                #pragma unroll
                for (int j = 0; j < DEG; ++j) {
                    const float2 bb = *(const float2*)(bond + (size_t)br[j] * 16 + q8 * 2);
                    bx += bb.x; by += bb.y;
                }
                unsigned short* pb = rowp + 128 + q8 * 2;
                pb[0] = f2bf(bx); pb[1] = f2bf(by);
            }
        }
        __syncthreads();

        // ---- MFMA: 32x288 @ 288x32 per wave ----
        floatx4 acc[2][2];
        #pragma unroll
        for (int mt = 0; mt < 2; ++mt)
            #pragma unroll
            for (int nt = 0; nt < 2; ++nt)
                acc[mt][nt] = (floatx4){0.f, 0.f, 0.f, 0.f};

        #pragma unroll
        for (int nt = 0; nt < 2; ++nt) {
            #pragma unroll
            for (int ks = 0; ks < 9; ++ks) {
                const short8 b = ((const short8*)pw)[(ks * 8 + wv * 2 + nt) * 64 + lane];
                const short8 af0 = *(const short8*)&A[ccol * LDA + ks * 32 + (crow << 3)];
                const short8 af1 = *(const short8*)&A[(16 + ccol) * LDA + ks * 32 + (crow << 3)];
                acc[0][nt] = __builtin_amdgcn_mfma_f32_16x16x32_bf16(af0, b, acc[0][nt], 0, 0, 0);
                acc[1][nt] = __builtin_amdgcn_mfma_f32_16x16x32_bf16(af1, b, acc[1][nt], 0, 0, 0);
            }
        }

        // ---- scatter + BN partials ----
        const int4 o0 = *reinterpret_cast<const int4*>(&own_lds[crow * 4]);
        const int4 o1 = *reinterpret_cast<const int4*>(&own_lds[16 + crow * 4]);
        const int owns[2][4] = {{o0.x, o0.y, o0.z, o0.w}, {o1.x, o1.y, o1.z, o1.w}};
        #pragma unroll
        for (int mt = 0; mt < 2; ++mt) {
            #pragma unroll
            for (int rr = 0; rr < 4; ++rr) {
                const int row = mt * 16 + crow * 4 + rr;
                if (i0 + row < n) {
                    const int o = owns[mt][rr];
                    #pragma unroll
                    for (int nt = 0; nt < 2; ++nt) {
                        const float v = acc[mt][nt][rr];
                        out[(size_t)o * 128 + nbase + nt * 16 + ccol] = v;
                        psum[nt] += v;
                        psq[nt]  += v * v;
                    }
                }
            }
        }
        __syncthreads();
    }

    // ---- per-block channel partials: waves own disjoint 32-col slices ----
    float* redS = reinterpret_cast<float*>(A);          // [128]
    float* redQ = redS + 128;                           // [128]
    #pragma unroll
    for (int nt = 0; nt < 2; ++nt) {
        float s = psum[nt], q = psq[nt];
        s += __shfl_xor(s, 16, 64); s += __shfl_xor(s, 32, 64);
        q += __shfl_xor(q, 16, 64); q += __shfl_xor(q, 32, 64);
        if (lane < 16) {
            redS[nbase + nt * 16 + lane] = s;
            redQ[nbase + nt * 16 + lane] = q;
        }
    }
}

// ---------------------------------------------------------------------------
// Fused kernel: 19.1 KB LDS -> 8 blocks/CU; forced 64-VGPR budget.
// ---------------------------------------------------------------------------
__global__ __launch_bounds__(256, 8) void gdc_mfma(
    const float* __restrict__ atom, const float* __restrict__ bond,
    const int* __restrict__ a1, const int* __restrict__ b1,
    const int* __restrict__ a2, const int* __restrict__ b2,
    const int* __restrict__ a3, const int* __restrict__ b3,
    const int* __restrict__ a4, const int* __restrict__ b4,
    const unsigned short* __restrict__ packedW,
    float* __restrict__ out,
    float* __restrict__ sumPart, float* __restrict__ sqPart)
{
    __shared__ __align__(16) unsigned short A[32 * LDA];   // 18944 B
    __shared__ __align__(16) int own_lds[32];

    const int tid  = threadIdx.x;
    const int wv   = tid >> 6;
    const int lane = tid & 63;
    const int blk  = blockIdx.x;

    int n, lb, nb, deg;
    const int* aidx; const int* bidx;
    if (blk < NB1)                 { deg = 1; n =  50000; lb = blk;                 nb = NB1; aidx = a1; bidx = b1; }
    else if (blk < NB1+NB2)        { deg = 2; n = 150000; lb = blk-NB1;             nb = NB2; aidx = a2; bidx = b2; }
    else if (blk < NB1+NB2+NB3)    { deg = 3; n = 200000; lb = blk-(NB1+NB2);       nb = NB3; aidx = a3; bidx = b3; }
    else                           { deg = 4; n = 100000; lb = blk-(NB1+NB2+NB3);   nb = NB4; aidx = a4; bidx = b4; }

    const unsigned short* pw = packedW + (size_t)(deg - 1) * SEG_ELEMS;

    // zero K-pad cols 272..287 once (never overwritten afterwards)
    {
        const int mm = tid >> 3, qq = tid & 7;
        ushort2 z; z.x = 0; z.y = 0;
        *reinterpret_cast<ushort2*>(&A[mm * LDA + 272 + qq * 2]) = z;
    }
    __syncthreads();

    switch (deg) {
    case 1:  block_loop<1>(atom, bond, aidx, bidx, pw, out, A, own_lds, n, lb, nb, tid, lane, wv); break;
    case 2:  block_loop<2>(atom, bond, aidx, bidx, pw, out, A, own_lds, n, lb, nb, tid, lane, wv); break;
    case 3:  block_loop<3>(atom, bond, aidx, bidx, pw, out, A, own_lds, n, lb, nb, tid, lane, wv); break;
    default: block_loop<4>(atom, bond, aidx, bidx, pw, out, A, own_lds, n, lb, nb, tid, lane, wv); break;
    }

    __syncthreads();
    const float* redS = reinterpret_cast<const float*>(A);
    if (tid < 128)      sumPart[(size_t)blk * 128 + tid] = redS[tid];
    else if (tid < 256) sqPart[(size_t)blk * 128 + (tid - 128)] = redS[tid];
}

// ---------------------------------------------------------------------------
// Reduce NBLK partials per channel -> mean, invstd (deterministic).
// ---------------------------------------------------------------------------
__global__ void gdc_stats(const float* __restrict__ sumPart,
                          const float* __restrict__ sqPart,
                          float* __restrict__ mv)
{
    const int c = blockIdx.x;
    const int j = threadIdx.x;
    __shared__ float rs[256], rq[256];
    float s = 0.f, q = 0.f;
    for (int b = j; b < NBLK; b += 256) {
        s += sumPart[(size_t)b * 128 + c];
        q += sqPart[(size_t)b * 128 + c];
    }
    rs[j] = s; rq[j] = q;
    __syncthreads();
    for (int off = 128; off > 0; off >>= 1) {
        if (j < off) { rs[j] += rs[j + off]; rq[j] += rq[j + off]; }
        __syncthreads();
    }
    if (j == 0) {
        const float mean = rs[0] / (float)N_ATOMS;
        const float var  = rq[0] / (float)N_ATOMS - mean * mean;
        mv[c]       = mean;
        mv[128 + c] = rsqrtf(var + EPS);
    }
}

// ---------------------------------------------------------------------------
// In-place normalize + ReLU. float4; per-thread channel loop-invariant.
// ---------------------------------------------------------------------------
__global__ __launch_bounds__(256) void gdc_norm(float* __restrict__ out,
                                                const float* __restrict__ mv)
{
    const size_t total4 = (size_t)N_ATOMS * 128 / 4;
    size_t idx = (size_t)blockIdx.x * 256 + threadIdx.x;
    const int c = (int)((idx * 4) & 127);
    const float4 m  = *(const float4*)(mv + c);
    const float4 iv = *(const float4*)(mv + 128 + c);
    const size_t stride = (size_t)gridDim.x * 256;
    for (; idx < total4; idx += stride) {
        float4 v = ((float4*)out)[idx];
        v.x = fmaxf(0.f, (v.x - m.x) * iv.x);
        v.y = fmaxf(0.f, (v.y - m.y) * iv.y);
        v.z = fmaxf(0.f, (v.z - m.z) * iv.z);
        v.w = fmaxf(0.f, (v.w - m.w) * iv.w);
        ((float4*)out)[idx] = v;
    }
}

extern "C" void kernel_launch(void* const* d_in, const int* in_sizes, int n_in,
                              void* d_out, int out_size, void* d_ws, size_t ws_size,
                              hipStream_t stream) {
    const float* atom  = (const float*)d_in[0];
    const float* bond  = (const float*)d_in[1];
    const int*   a1    = (const int*)d_in[2];
    const int*   b1    = (const int*)d_in[3];
    const int*   a2    = (const int*)d_in[4];
    const int*   b2    = (const int*)d_in[5];
    const int*   a3    = (const int*)d_in[6];
    const int*   b3    = (const int*)d_in[7];
    const int*   a4    = (const int*)d_in[8];
    const int*   b4    = (const int*)d_in[9];
    const float* Wself = (const float*)d_in[10];
    const float* W1    = (const float*)d_in[11];
    const float* W2    = (const float*)d_in[12];
    const float* W3    = (const float*)d_in[13];
    const float* W4    = (const float*)d_in[14];
    // bias cancels under BatchNorm (shift-invariance; verified R5) -> unused
    float* out = (float*)d_out;

    // ws layout: packedW (294912 B) | sumPart[NBLK*128] | sqPart[NBLK*128] | mv[256]
    unsigned short* packedW = (unsigned short*)d_ws;
    float* sumPart = (float*)((char*)d_ws + 4 * SEG_ELEMS * sizeof(unsigned short));
    float* sqPart  = sumPart + (size_t)NBLK * 128;
    float* mv      = sqPart + (size_t)NBLK * 128;

    hipLaunchKernelGGL(gdc_pack, dim3((4*9*8*64 + 255)/256), dim3(256), 0, stream,
                       W1, W2, W3, W4, Wself, packedW);
    hipLaunchKernelGGL(gdc_mfma, dim3(NBLK), dim3(256), 0, stream,
                       atom, bond, a1, b1, a2, b2, a3, b3, a4, b4,
                       packedW, out, sumPart, sqPart);
    hipLaunchKernelGGL(gdc_stats, dim3(128), dim3(256), 0, stream,
                       sumPart, sqPart, mv);
    hipLaunchKernelGGL(gdc_norm, dim3(2048), dim3(256), 0, stream, out, mv);
}

// Round 8
// 563.025 us; speedup vs baseline: 1.0188x; 1.0188x over previous
//
#include <hip/hip_runtime.h>
#include <hip/hip_bf16.h>
#include <math.h>

#define N_ATOMS 500000
#define EPS 1e-5f
#define LDA 296   // bf16 elems per A row: 288 + 8 pad (breaks bank aliasing)

// blocks per degree segment (2048 blocks), proportional to gather volume
#define NB1 111
#define NB2 498
#define NB3 886
#define NB4 553
#define NBLK 2048

#define SEG_ELEMS 36864   // 288*128 bf16 per packed weight segment

typedef __attribute__((ext_vector_type(8))) short short8;
typedef __attribute__((ext_vector_type(4))) float floatx4;

__device__ __forceinline__ unsigned short f2bf(float f) {
    unsigned int x = __float_as_uint(f);
    x += 0x7FFF + ((x >> 16) & 1);          // round-to-nearest-even
    return (unsigned short)(x >> 16);
}

__device__ __forceinline__ float4 add4(float4 a, float4 b) {
    return make_float4(a.x + b.x, a.y + b.y, a.z + b.z, a.w + b.w);
}

__device__ __forceinline__ void st_bf4(unsigned short* p, float4 v) {
    ushort4 u;
    u.x = f2bf(v.x); u.y = f2bf(v.y); u.z = f2bf(v.z); u.w = f2bf(v.w);
    *reinterpret_cast<ushort4*>(p) = u;     // ds_write_b64
}

// ---------------------------------------------------------------------------
// Pack weights into MFMA B-fragment layout, bf16.
// packed[d]: (ks 0..8, ntg 0..7, lane 0..63) -> short8; col = ntg*16+(lane&15),
// k = ks*32 + (lane>>4)*8 + j; k<144 -> W_d rows, k<272 -> W_self, else 0.
// ---------------------------------------------------------------------------
__global__ __launch_bounds__(256) void gdc_pack(
    const float* __restrict__ W1, const float* __restrict__ W2,
    const float* __restrict__ W3, const float* __restrict__ W4,
    const float* __restrict__ Wself, unsigned short* __restrict__ packed)
{
    const int t = blockIdx.x * 256 + threadIdx.x;
    if (t >= 4 * 9 * 8 * 64) return;
    const int d    = t / 4608;
    const int r    = t % 4608;
    const int ks   = r / 512;
    const int nt   = (r % 512) / 64;
    const int lane = r % 64;
    const float* Wd = (d == 0) ? W1 : (d == 1) ? W2 : (d == 2) ? W3 : W4;
    const int col = nt * 16 + (lane & 15);
    short8 v;
    #pragma unroll
    for (int j = 0; j < 8; ++j) {
        const int k = ks * 32 + ((lane >> 4) << 3) + j;
        float w = 0.f;
        if (k < 144)      w = Wd[k * 128 + col];
        else if (k < 272) w = Wself[(k - 144) * 128 + col];
        v[j] = (short)f2bf(w);
    }
    *reinterpret_cast<short8*>(packed + (size_t)d * SEG_ELEMS
                               + ((size_t)(ks * 8 + nt) * 64 + lane) * 8) = v;
}

// ---------------------------------------------------------------------------
// Block loop: 4 waves share one 32-row A tile. Wave wv owns cols [32wv,32wv+32).
// A K-layout: [a_sum 0..127 | b_sum 128..143 | self 144..271 | pad 272..287].
// ---------------------------------------------------------------------------
template <int DEG>
__device__ __forceinline__ void block_loop(
    const float* __restrict__ atom, const float* __restrict__ bond,
    const int* __restrict__ aidx, const int* __restrict__ bidx,
    const unsigned short* __restrict__ pw,
    float* __restrict__ out,
    unsigned short* __restrict__ A, int* __restrict__ own_lds,
    int n, int lb, int nb, int tid, int lane, int wv)
{
    const int m    = tid >> 3;           // node row 0..31 (block-wide gather)
    const int q8   = tid & 7;            // k-slice 0..7 (16 floats each)
    const int ccol = lane & 15;          // C col within 16-tile / A frag row
    const int crow = lane >> 4;          // C row group 0..3
    const int nbase = wv * 32;

    float psum[2] = {0.f, 0.f}, psq[2] = {0.f, 0.f};

    const int tiles = (n + 31) >> 5;

    for (int t = lb; t < tiles; t += nb) {
        const int i0 = t << 5;
        const int i = i0 + m;

        // ---- gather: 32 nodes x 8 slices across 256 threads ----
        if (i < n) {
            const int* ar = aidx + (size_t)i * (DEG + 1);
            const int own = ar[0];
            if (q8 == 0) own_lds[m] = own;
            const float4* s = (const float4*)(atom + (size_t)own * 128 + q8 * 16);
            float4 a0 = s[0], a1 = s[1], a2 = s[2], a3 = s[3];
            unsigned short* rowp = A + m * LDA;
            // self slice -> cols 144 + q8*16
            st_bf4(rowp + 144 + q8 * 16 + 0,  a0);
            st_bf4(rowp + 144 + q8 * 16 + 4,  a1);
            st_bf4(rowp + 144 + q8 * 16 + 8,  a2);
            st_bf4(rowp + 144 + q8 * 16 + 12, a3);
            #pragma unroll
            for (int j = 1; j <= DEG; ++j) {
                const float4* p = (const float4*)(atom + (size_t)ar[j] * 128 + q8 * 16);
                a0 = add4(a0, p[0]); a1 = add4(a1, p[1]);
                a2 = add4(a2, p[2]); a3 = add4(a3, p[3]);
            }
            st_bf4(rowp + q8 * 16 + 0,  a0);
            st_bf4(rowp + q8 * 16 + 4,  a1);
            st_bf4(rowp + q8 * 16 + 8,  a2);
            st_bf4(rowp + q8 * 16 + 12, a3);
            // bonds: this thread covers 2 of 16 cols
            {
                const int* br = bidx + (size_t)i * DEG;
                float bx = 0.f, by = 0.f;
                #pragma unroll
                for (int j = 0; j < DEG; ++j) {
                    const float2 bb = *(const float2*)(bond + (size_t)br[j] * 16 + q8 * 2);
                    bx += bb.x; by += bb.y;
                }
                unsigned short* pb = rowp + 128 + q8 * 2;
                pb[0] = f2bf(bx); pb[1] = f2bf(by);
            }
        }
        __syncthreads();

        // ---- MFMA: 32x288 @ 288x32 per wave (ks outer: af read once per ks) ----
        floatx4 acc[2][2];
        #pragma unroll
        for (int mt = 0; mt < 2; ++mt)
            #pragma unroll
            for (int nt = 0; nt < 2; ++nt)
                acc[mt][nt] = (floatx4){0.f, 0.f, 0.f, 0.f};

        #pragma unroll
        for (int ks = 0; ks < 9; ++ks) {
            const short8 af0 = *(const short8*)&A[ccol * LDA + ks * 32 + (crow << 3)];
            const short8 af1 = *(const short8*)&A[(16 + ccol) * LDA + ks * 32 + (crow << 3)];
            #pragma unroll
            for (int nt = 0; nt < 2; ++nt) {
                const short8 b = ((const short8*)pw)[(ks * 8 + wv * 2 + nt) * 64 + lane];
                acc[0][nt] = __builtin_amdgcn_mfma_f32_16x16x32_bf16(af0, b, acc[0][nt], 0, 0, 0);
                acc[1][nt] = __builtin_amdgcn_mfma_f32_16x16x32_bf16(af1, b, acc[1][nt], 0, 0, 0);
            }
        }

        // ---- scatter + BN partials ----
        const int4 o0 = *reinterpret_cast<const int4*>(&own_lds[crow * 4]);
        const int4 o1 = *reinterpret_cast<const int4*>(&own_lds[16 + crow * 4]);
        const int owns[2][4] = {{o0.x, o0.y, o0.z, o0.w}, {o1.x, o1.y, o1.z, o1.w}};
        #pragma unroll
        for (int mt = 0; mt < 2; ++mt) {
            #pragma unroll
            for (int rr = 0; rr < 4; ++rr) {
                const int row = mt * 16 + crow * 4 + rr;
                if (i0 + row < n) {
                    const int o = owns[mt][rr];
                    #pragma unroll
                    for (int nt = 0; nt < 2; ++nt) {
                        const float v = acc[mt][nt][rr];
                        out[(size_t)o * 128 + nbase + nt * 16 + ccol] = v;
                        psum[nt] += v;
                        psq[nt]  += v * v;
                    }
                }
            }
        }
        __syncthreads();
    }

    // ---- per-block channel partials: waves own disjoint 32-col slices ----
    float* redS = reinterpret_cast<float*>(A);          // [128]
    float* redQ = redS + 128;                           // [128]
    #pragma unroll
    for (int nt = 0; nt < 2; ++nt) {
        float s = psum[nt], q = psq[nt];
        s += __shfl_xor(s, 16, 64); s += __shfl_xor(s, 32, 64);
        q += __shfl_xor(q, 16, 64); q += __shfl_xor(q, 32, 64);
        if (lane < 16) {
            redS[nbase + nt * 16 + lane] = s;
            redQ[nbase + nt * 16 + lane] = q;
        }
    }
}

// ---------------------------------------------------------------------------
// Fused kernel: 19.5 KB LDS; 6 waves/EU target -> ~84 VGPR budget, no spill.
// ---------------------------------------------------------------------------
__global__ __launch_bounds__(256, 6) void gdc_mfma(
    const float* __restrict__ atom, const float* __restrict__ bond,
    const int* __restrict__ a1, const int* __restrict__ b1,
    const int* __restrict__ a2, const int* __restrict__ b2,
    const int* __restrict__ a3, const int* __restrict__ b3,
    const int* __restrict__ a4, const int* __restrict__ b4,
    const unsigned short* __restrict__ packedW,
    float* __restrict__ out,
    float* __restrict__ sumPart, float* __restrict__ sqPart)
{
    __shared__ __align__(16) unsigned short A[32 * LDA];   // 18944 B
    __shared__ __align__(16) int own_lds[32];

    const int tid  = threadIdx.x;
    const int wv   = tid >> 6;
    const int lane = tid & 63;
    const int blk  = blockIdx.x;

    int n, lb, nb, deg;
    const int* aidx; const int* bidx;
    if (blk < NB1)                 { deg = 1; n =  50000; lb = blk;                 nb = NB1; aidx = a1; bidx = b1; }
    else if (blk < NB1+NB2)        { deg = 2; n = 150000; lb = blk-NB1;             nb = NB2; aidx = a2; bidx = b2; }
    else if (blk < NB1+NB2+NB3)    { deg = 3; n = 200000; lb = blk-(NB1+NB2);       nb = NB3; aidx = a3; bidx = b3; }
    else                           { deg = 4; n = 100000; lb = blk-(NB1+NB2+NB3);   nb = NB4; aidx = a4; bidx = b4; }

    const unsigned short* pw = packedW + (size_t)(deg - 1) * SEG_ELEMS;

    // zero K-pad cols 272..287 once (never overwritten afterwards)
    {
        const int mm = tid >> 3, qq = tid & 7;
        ushort2 z; z.x = 0; z.y = 0;
        *reinterpret_cast<ushort2*>(&A[mm * LDA + 272 + qq * 2]) = z;
    }
    __syncthreads();

    switch (deg) {
    case 1:  block_loop<1>(atom, bond, aidx, bidx, pw, out, A, own_lds, n, lb, nb, tid, lane, wv); break;
    case 2:  block_loop<2>(atom, bond, aidx, bidx, pw, out, A, own_lds, n, lb, nb, tid, lane, wv); break;
    case 3:  block_loop<3>(atom, bond, aidx, bidx, pw, out, A, own_lds, n, lb, nb, tid, lane, wv); break;
    default: block_loop<4>(atom, bond, aidx, bidx, pw, out, A, own_lds, n, lb, nb, tid, lane, wv); break;
    }

    __syncthreads();
    const float* redS = reinterpret_cast<const float*>(A);
    if (tid < 128)      sumPart[(size_t)blk * 128 + tid] = redS[tid];
    else if (tid < 256) sqPart[(size_t)blk * 128 + (tid - 128)] = redS[tid];
}

// ---------------------------------------------------------------------------
// Reduce NBLK partials per channel -> mean, invstd (deterministic).
// ---------------------------------------------------------------------------
__global__ void gdc_stats(const float* __restrict__ sumPart,
                          const float* __restrict__ sqPart,
                          float* __restrict__ mv)
{
    const int c = blockIdx.x;
    const int j = threadIdx.x;
    __shared__ float rs[256], rq[256];
    float s = 0.f, q = 0.f;
    for (int b = j; b < NBLK; b += 256) {
        s += sumPart[(size_t)b * 128 + c];
        q += sqPart[(size_t)b * 128 + c];
    }
    rs[j] = s; rq[j] = q;
    __syncthreads();
    for (int off = 128; off > 0; off >>= 1) {
        if (j < off) { rs[j] += rs[j + off]; rq[j] += rq[j + off]; }
        __syncthreads();
    }
    if (j == 0) {
        const float mean = rs[0] / (float)N_ATOMS;
        const float var  = rq[0] / (float)N_ATOMS - mean * mean;
        mv[c]       = mean;
        mv[128 + c] = rsqrtf(var + EPS);
    }
}

// ---------------------------------------------------------------------------
// In-place normalize + ReLU. float4; per-thread channel loop-invariant.
// ---------------------------------------------------------------------------
__global__ __launch_bounds__(256) void gdc_norm(float* __restrict__ out,
                                                const float* __restrict__ mv)
{
    const size_t total4 = (size_t)N_ATOMS * 128 / 4;
    size_t idx = (size_t)blockIdx.x * 256 + threadIdx.x;
    const int c = (int)((idx * 4) & 127);
    const float4 m  = *(const float4*)(mv + c);
    const float4 iv = *(const float4*)(mv + 128 + c);
    const size_t stride = (size_t)gridDim.x * 256;
    for (; idx < total4; idx += stride) {
        float4 v = ((float4*)out)[idx];
        v.x = fmaxf(0.f, (v.x - m.x) * iv.x);
        v.y = fmaxf(0.f, (v.y - m.y) * iv.y);
        v.z = fmaxf(0.f, (v.z - m.z) * iv.z);
        v.w = fmaxf(0.f, (v.w - m.w) * iv.w);
        ((float4*)out)[idx] = v;
    }
}

extern "C" void kernel_launch(void* const* d_in, const int* in_sizes, int n_in,
                              void* d_out, int out_size, void* d_ws, size_t ws_size,
                              hipStream_t stream) {
    const float* atom  = (const float*)d_in[0];
    const float* bond  = (const float*)d_in[1];
    const int*   a1    = (const int*)d_in[2];
    const int*   b1    = (const int*)d_in[3];
    const int*   a2    = (const int*)d_in[4];
    const int*   b2    = (const int*)d_in[5];
    const int*   a3    = (const int*)d_in[6];
    const int*   b3    = (const int*)d_in[7];
    const int*   a4    = (const int*)d_in[8];
    const int*   b4    = (const int*)d_in[9];
    const float* Wself = (const float*)d_in[10];
    const float* W1    = (const float*)d_in[11];
    const float* W2    = (const float*)d_in[12];
    const float* W3    = (const float*)d_in[13];
    const float* W4    = (const float*)d_in[14];
    // bias cancels under BatchNorm (shift-invariance; verified R5/R6) -> unused
    float* out = (float*)d_out;

    // ws layout: packedW (294912 B) | sumPart[NBLK*128] | sqPart[NBLK*128] | mv[256]
    unsigned short* packedW = (unsigned short*)d_ws;
    float* sumPart = (float*)((char*)d_ws + 4 * SEG_ELEMS * sizeof(unsigned short));
    float* sqPart  = sumPart + (size_t)NBLK * 128;
    float* mv      = sqPart + (size_t)NBLK * 128;

    hipLaunchKernelGGL(gdc_pack, dim3((4*9*8*64 + 255)/256), dim3(256), 0, stream,
                       W1, W2, W3, W4, Wself, packedW);
    hipLaunchKernelGGL(gdc_mfma, dim3(NBLK), dim3(256), 0, stream,
                       atom, bond, a1, b1, a2, b2, a3, b3, a4, b4,
                       packedW, out, sumPart, sqPart);
    hipLaunchKernelGGL(gdc_stats, dim3(128), dim3(256), 0, stream,
                       sumPart, sqPart, mv);
    hipLaunchKernelGGL(gdc_norm, dim3(2048), dim3(256), 0, stream, out, mv);
}

// Round 9
// 406.418 us; speedup vs baseline: 1.4114x; 1.3853x over previous
//
#include <hip/hip_runtime.h>
#include <hip/hip_bf16.h>
#include <math.h>

#define N_ATOMS 500000
#define EPS 1e-5f
#define LDA 296   // bf16 elems per A row: 288 + 8 pad (breaks bank aliasing)

// blocks per degree segment (2048 blocks), proportional to gather volume
#define NB1 111
#define NB2 498
#define NB3 886
#define NB4 553
#define NBLK 2048

#define SEG_ELEMS 36864   // 288*128 bf16 per packed weight segment

typedef __attribute__((ext_vector_type(8))) short short8;
typedef __attribute__((ext_vector_type(4))) float floatx4;

__device__ __forceinline__ unsigned short f2bf(float f) {
    unsigned int x = __float_as_uint(f);
    x += 0x7FFF + ((x >> 16) & 1);          // round-to-nearest-even
    return (unsigned short)(x >> 16);
}

__device__ __forceinline__ float4 add4(float4 a, float4 b) {
    return make_float4(a.x + b.x, a.y + b.y, a.z + b.z, a.w + b.w);
}

__device__ __forceinline__ void st_bf4(unsigned short* p, float4 v) {
    ushort4 u;
    u.x = f2bf(v.x); u.y = f2bf(v.y); u.z = f2bf(v.z); u.w = f2bf(v.w);
    *reinterpret_cast<ushort4*>(p) = u;     // ds_write_b64
}

// ---------------------------------------------------------------------------
// Pack weights into MFMA B-fragment layout, bf16.
// packed[d]: (ks 0..8, ntg 0..7, lane 0..63) -> short8; col = ntg*16+(lane&15),
// k = ks*32 + (lane>>4)*8 + j; k<144 -> W_d rows, k<272 -> W_self, else 0.
// ---------------------------------------------------------------------------
__global__ __launch_bounds__(256) void gdc_pack(
    const float* __restrict__ W1, const float* __restrict__ W2,
    const float* __restrict__ W3, const float* __restrict__ W4,
    const float* __restrict__ Wself, unsigned short* __restrict__ packed)
{
    const int t = blockIdx.x * 256 + threadIdx.x;
    if (t >= 4 * 9 * 8 * 64) return;
    const int d    = t / 4608;
    const int r    = t % 4608;
    const int ks   = r / 512;
    const int nt   = (r % 512) / 64;
    const int lane = r % 64;
    const float* Wd = (d == 0) ? W1 : (d == 1) ? W2 : (d == 2) ? W3 : W4;
    const int col = nt * 16 + (lane & 15);
    short8 v;
    #pragma unroll
    for (int j = 0; j < 8; ++j) {
        const int k = ks * 32 + ((lane >> 4) << 3) + j;
        float w = 0.f;
        if (k < 144)      w = Wd[k * 128 + col];
        else if (k < 272) w = Wself[(k - 144) * 128 + col];
        v[j] = (short)f2bf(w);
    }
    *reinterpret_cast<short8*>(packed + (size_t)d * SEG_ELEMS
                               + ((size_t)(ks * 8 + nt) * 64 + lane) * 8) = v;
}

// ---------------------------------------------------------------------------
// Block loop: 4 waves share one 32-row A tile. Wave wv owns cols [32wv,32wv+32).
// A K-layout: [a_sum 0..127 | b_sum 128..143 | self 144..271 | pad 272..287].
// Next tile's atom-index row is prefetched into registers during compute.
// ---------------------------------------------------------------------------
template <int DEG>
__device__ __forceinline__ void block_loop(
    const float* __restrict__ atom, const float* __restrict__ bond,
    const int* __restrict__ aidx, const int* __restrict__ bidx,
    const unsigned short* __restrict__ pw,
    float* __restrict__ out,
    unsigned short* __restrict__ A, int* __restrict__ own_lds,
    int n, int lb, int nb, int tid, int lane, int wv)
{
    const int m    = tid >> 3;           // node row 0..31 (block-wide gather)
    const int q8   = tid & 7;            // k-slice 0..7 (16 floats each)
    const int ccol = lane & 15;          // C col within 16-tile / A frag row
    const int crow = lane >> 4;          // C row group 0..3
    const int nbase = wv * 32;

    float psum[2] = {0.f, 0.f}, psq[2] = {0.f, 0.f};

    const int tiles = (n + 31) >> 5;

    // preload first tile's atom-index row
    int ar_c[DEG + 1];
    if (lb < tiles) {
        const int i = (lb << 5) + m;
        if (i < n) {
            const int* ar = aidx + (size_t)i * (DEG + 1);
            #pragma unroll
            for (int j = 0; j <= DEG; ++j) ar_c[j] = ar[j];
        }
    }

    for (int t = lb; t < tiles; t += nb) {
        const int i0 = t << 5;
        const int i = i0 + m;

        // ---- gather: 32 nodes x 8 slices across 256 threads ----
        if (i < n) {
            const int own = ar_c[0];
            if (q8 == 0) own_lds[m] = own;
            const float4* s = (const float4*)(atom + (size_t)own * 128 + q8 * 16);
            float4 a0 = s[0], a1 = s[1], a2 = s[2], a3 = s[3];
            unsigned short* rowp = A + m * LDA;
            // self slice -> cols 144 + q8*16
            st_bf4(rowp + 144 + q8 * 16 + 0,  a0);
            st_bf4(rowp + 144 + q8 * 16 + 4,  a1);
            st_bf4(rowp + 144 + q8 * 16 + 8,  a2);
            st_bf4(rowp + 144 + q8 * 16 + 12, a3);
            #pragma unroll
            for (int j = 1; j <= DEG; ++j) {
                const float4* p = (const float4*)(atom + (size_t)ar_c[j] * 128 + q8 * 16);
                a0 = add4(a0, p[0]); a1 = add4(a1, p[1]);
                a2 = add4(a2, p[2]); a3 = add4(a3, p[3]);
            }
            st_bf4(rowp + q8 * 16 + 0,  a0);
            st_bf4(rowp + q8 * 16 + 4,  a1);
            st_bf4(rowp + q8 * 16 + 8,  a2);
            st_bf4(rowp + q8 * 16 + 12, a3);
            // bonds: this thread covers 2 of 16 cols
            {
                const int* br = bidx + (size_t)i * DEG;
                float bx = 0.f, by = 0.f;
                #pragma unroll
                for (int j = 0; j < DEG; ++j) {
                    const float2 bb = *(const float2*)(bond + (size_t)br[j] * 16 + q8 * 2);
                    bx += bb.x; by += bb.y;
                }
                unsigned short* pb = rowp + 128 + q8 * 2;
                pb[0] = f2bf(bx); pb[1] = f2bf(by);
            }
        }

        // ---- prefetch next tile's atom-index row (hides under MFMA) ----
        {
            const int t2 = t + nb;
            if (t2 < tiles) {
                const int i2 = (t2 << 5) + m;
                if (i2 < n) {
                    const int* ar = aidx + (size_t)i2 * (DEG + 1);
                    #pragma unroll
                    for (int j = 0; j <= DEG; ++j) ar_c[j] = ar[j];
                }
            }
        }
        __syncthreads();

        // ---- MFMA: 32x288 @ 288x32 per wave (ks outer: af read once per ks) ----
        floatx4 acc[2][2];
        #pragma unroll
        for (int mt = 0; mt < 2; ++mt)
            #pragma unroll
            for (int nt = 0; nt < 2; ++nt)
                acc[mt][nt] = (floatx4){0.f, 0.f, 0.f, 0.f};

        #pragma unroll
        for (int ks = 0; ks < 9; ++ks) {
            const short8 af0 = *(const short8*)&A[ccol * LDA + ks * 32 + (crow << 3)];
            const short8 af1 = *(const short8*)&A[(16 + ccol) * LDA + ks * 32 + (crow << 3)];
            #pragma unroll
            for (int nt = 0; nt < 2; ++nt) {
                const short8 b = ((const short8*)pw)[(ks * 8 + wv * 2 + nt) * 64 + lane];
                acc[0][nt] = __builtin_amdgcn_mfma_f32_16x16x32_bf16(af0, b, acc[0][nt], 0, 0, 0);
                acc[1][nt] = __builtin_amdgcn_mfma_f32_16x16x32_bf16(af1, b, acc[1][nt], 0, 0, 0);
            }
        }

        // ---- scatter + BN partials ----
        const int4 o0 = *reinterpret_cast<const int4*>(&own_lds[crow * 4]);
        const int4 o1 = *reinterpret_cast<const int4*>(&own_lds[16 + crow * 4]);
        const int owns[2][4] = {{o0.x, o0.y, o0.z, o0.w}, {o1.x, o1.y, o1.z, o1.w}};
        #pragma unroll
        for (int mt = 0; mt < 2; ++mt) {
            #pragma unroll
            for (int rr = 0; rr < 4; ++rr) {
                const int row = mt * 16 + crow * 4 + rr;
                if (i0 + row < n) {
                    const int o = owns[mt][rr];
                    #pragma unroll
                    for (int nt = 0; nt < 2; ++nt) {
                        const float v = acc[mt][nt][rr];
                        out[(size_t)o * 128 + nbase + nt * 16 + ccol] = v;
                        psum[nt] += v;
                        psq[nt]  += v * v;
                    }
                }
            }
        }
        __syncthreads();
    }

    // ---- per-block channel partials: waves own disjoint 32-col slices ----
    float* redS = reinterpret_cast<float*>(A);          // [128]
    float* redQ = redS + 128;                           // [128]
    #pragma unroll
    for (int nt = 0; nt < 2; ++nt) {
        float s = psum[nt], q = psq[nt];
        s += __shfl_xor(s, 16, 64); s += __shfl_xor(s, 32, 64);
        q += __shfl_xor(q, 16, 64); q += __shfl_xor(q, 32, 64);
        if (lane < 16) {
            redS[nbase + nt * 16 + lane] = s;
            redQ[nbase + nt * 16 + lane] = q;
        }
    }
}

// ---------------------------------------------------------------------------
// Fused kernel: 19.5 KB LDS -> 8 blocks/CU if natural VGPR <= 64; no forced cap.
// ---------------------------------------------------------------------------
__global__ __launch_bounds__(256, 4) void gdc_mfma(
    const float* __restrict__ atom, const float* __restrict__ bond,
    const int* __restrict__ a1, const int* __restrict__ b1,
    const int* __restrict__ a2, const int* __restrict__ b2,
    const int* __restrict__ a3, const int* __restrict__ b3,
    const int* __restrict__ a4, const int* __restrict__ b4,
    const unsigned short* __restrict__ packedW,
    float* __restrict__ out,
    float* __restrict__ sumPart, float* __restrict__ sqPart)
{
    __shared__ __align__(16) unsigned short A[32 * LDA];   // 18944 B
    __shared__ __align__(16) int own_lds[32];

    const int tid  = threadIdx.x;
    const int wv   = tid >> 6;
    const int lane = tid & 63;
    const int blk  = blockIdx.x;

    int n, lb, nb, deg;
    const int* aidx; const int* bidx;
    if (blk < NB1)                 { deg = 1; n =  50000; lb = blk;                 nb = NB1; aidx = a1; bidx = b1; }
    else if (blk < NB1+NB2)        { deg = 2; n = 150000; lb = blk-NB1;             nb = NB2; aidx = a2; bidx = b2; }
    else if (blk < NB1+NB2+NB3)    { deg = 3; n = 200000; lb = blk-(NB1+NB2);       nb = NB3; aidx = a3; bidx = b3; }
    else                           { deg = 4; n = 100000; lb = blk-(NB1+NB2+NB3);   nb = NB4; aidx = a4; bidx = b4; }

    const unsigned short* pw = packedW + (size_t)(deg - 1) * SEG_ELEMS;

    // zero K-pad cols 272..287 once (never overwritten afterwards)
    {
        const int mm = tid >> 3, qq = tid & 7;
        ushort2 z; z.x = 0; z.y = 0;
        *reinterpret_cast<ushort2*>(&A[mm * LDA + 272 + qq * 2]) = z;
    }
    __syncthreads();

    switch (deg) {
    case 1:  block_loop<1>(atom, bond, aidx, bidx, pw, out, A, own_lds, n, lb, nb, tid, lane, wv); break;
    case 2:  block_loop<2>(atom, bond, aidx, bidx, pw, out, A, own_lds, n, lb, nb, tid, lane, wv); break;
    case 3:  block_loop<3>(atom, bond, aidx, bidx, pw, out, A, own_lds, n, lb, nb, tid, lane, wv); break;
    default: block_loop<4>(atom, bond, aidx, bidx, pw, out, A, own_lds, n, lb, nb, tid, lane, wv); break;
    }

    __syncthreads();
    const float* redS = reinterpret_cast<const float*>(A);
    if (tid < 128)      sumPart[(size_t)blk * 128 + tid] = redS[tid];
    else if (tid < 256) sqPart[(size_t)blk * 128 + (tid - 128)] = redS[tid];
}

// ---------------------------------------------------------------------------
// Reduce NBLK partials per channel -> mean, invstd (deterministic).
// ---------------------------------------------------------------------------
__global__ void gdc_stats(const float* __restrict__ sumPart,
                          const float* __restrict__ sqPart,
                          float* __restrict__ mv)
{
    const int c = blockIdx.x;
    const int j = threadIdx.x;
    __shared__ float rs[256], rq[256];
    float s = 0.f, q = 0.f;
    for (int b = j; b < NBLK; b += 256) {
        s += sumPart[(size_t)b * 128 + c];
        q += sqPart[(size_t)b * 128 + c];
    }
    rs[j] = s; rq[j] = q;
    __syncthreads();
    for (int off = 128; off > 0; off >>= 1) {
        if (j < off) { rs[j] += rs[j + off]; rq[j] += rq[j + off]; }
        __syncthreads();
    }
    if (j == 0) {
        const float mean = rs[0] / (float)N_ATOMS;
        const float var  = rq[0] / (float)N_ATOMS - mean * mean;
        mv[c]       = mean;
        mv[128 + c] = rsqrtf(var + EPS);
    }
}

// ---------------------------------------------------------------------------
// In-place normalize + ReLU. float4; per-thread channel loop-invariant.
// ---------------------------------------------------------------------------
__global__ __launch_bounds__(256) void gdc_norm(float* __restrict__ out,
                                                const float* __restrict__ mv)
{
    const size_t total4 = (size_t)N_ATOMS * 128 / 4;
    size_t idx = (size_t)blockIdx.x * 256 + threadIdx.x;
    const int c = (int)((idx * 4) & 127);
    const float4 m  = *(const float4*)(mv + c);
    const float4 iv = *(const float4*)(mv + 128 + c);
    const size_t stride = (size_t)gridDim.x * 256;
    for (; idx < total4; idx += stride) {
        float4 v = ((float4*)out)[idx];
        v.x = fmaxf(0.f, (v.x - m.x) * iv.x);
        v.y = fmaxf(0.f, (v.y - m.y) * iv.y);
        v.z = fmaxf(0.f, (v.z - m.z) * iv.z);
        v.w = fmaxf(0.f, (v.w - m.w) * iv.w);
        ((float4*)out)[idx] = v;
    }
}

extern "C" void kernel_launch(void* const* d_in, const int* in_sizes, int n_in,
                              void* d_out, int out_size, void* d_ws, size_t ws_size,
                              hipStream_t stream) {
    const float* atom  = (const float*)d_in[0];
    const float* bond  = (const float*)d_in[1];
    const int*   a1    = (const int*)d_in[2];
    const int*   b1    = (const int*)d_in[3];
    const int*   a2    = (const int*)d_in[4];
    const int*   b2    = (const int*)d_in[5];
    const int*   a3    = (const int*)d_in[6];
    const int*   b3    = (const int*)d_in[7];
    const int*   a4    = (const int*)d_in[8];
    const int*   b4    = (const int*)d_in[9];
    const float* Wself = (const float*)d_in[10];
    const float* W1    = (const float*)d_in[11];
    const float* W2    = (const float*)d_in[12];
    const float* W3    = (const float*)d_in[13];
    const float* W4    = (const float*)d_in[14];
    // bias cancels under BatchNorm (shift-invariance; verified R5/R6) -> unused
    float* out = (float*)d_out;

    // ws layout: packedW (294912 B) | sumPart[NBLK*128] | sqPart[NBLK*128] | mv[256]
    unsigned short* packedW = (unsigned short*)d_ws;
    float* sumPart = (float*)((char*)d_ws + 4 * SEG_ELEMS * sizeof(unsigned short));
    float* sqPart  = sumPart + (size_t)NBLK * 128;
    float* mv      = sqPart + (size_t)NBLK * 128;

    hipLaunchKernelGGL(gdc_pack, dim3((4*9*8*64 + 255)/256), dim3(256), 0, stream,
                       W1, W2, W3, W4, Wself, packedW);
    hipLaunchKernelGGL(gdc_mfma, dim3(NBLK), dim3(256), 0, stream,
                       atom, bond, a1, b1, a2, b2, a3, b3, a4, b4,
                       packedW, out, sumPart, sqPart);
    hipLaunchKernelGGL(gdc_stats, dim3(128), dim3(256), 0, stream,
                       sumPart, sqPart, mv);
    hipLaunchKernelGGL(gdc_norm, dim3(2048), dim3(256), 0, stream, out, mv);
}

// Round 10
// 351.903 us; speedup vs baseline: 1.6300x; 1.1549x over previous
//
#include <hip/hip_runtime.h>
#include <hip/hip_bf16.h>
#include <math.h>

#define N_ATOMS 500000
#define EPS 1e-5f
#define LDA 296   // bf16 elems per A row: 288 + 8 pad

// blocks per degree segment (1024 blocks), proportional to gather volume n_d*(d+1)
#define NB1 55
#define NB2 249
#define NB3 443
#define NB4 277
#define NBLK 1024

#define SEG_ELEMS 36864   // 288*128 bf16 per packed weight segment

typedef __attribute__((ext_vector_type(8))) short short8;
typedef __attribute__((ext_vector_type(4))) float floatx4;

__device__ __forceinline__ unsigned short f2bf(float f) {
    unsigned int x = __float_as_uint(f);
    x += 0x7FFF + ((x >> 16) & 1);          // round-to-nearest-even
    return (unsigned short)(x >> 16);
}

__device__ __forceinline__ float4 add4(float4 a, float4 b) {
    return make_float4(a.x + b.x, a.y + b.y, a.z + b.z, a.w + b.w);
}

__device__ __forceinline__ void st_bf4(unsigned short* p, float4 v) {
    ushort4 u;
    u.x = f2bf(v.x); u.y = f2bf(v.y); u.z = f2bf(v.z); u.w = f2bf(v.w);
    *reinterpret_cast<ushort4*>(p) = u;     // ds_write_b64
}

// ---------------------------------------------------------------------------
// Pack weights into MFMA B-fragment layout, bf16.
// packed[d]: (ks 0..8, nt 0..7, lane 0..63) -> short8; col = nt*16+(lane&15),
// k = ks*32 + (lane>>4)*8 + j; k<144 -> W_d rows, k<272 -> W_self, else 0.
// ---------------------------------------------------------------------------
__global__ __launch_bounds__(256) void gdc_pack(
    const float* __restrict__ W1, const float* __restrict__ W2,
    const float* __restrict__ W3, const float* __restrict__ W4,
    const float* __restrict__ Wself, unsigned short* __restrict__ packed)
{
    const int t = blockIdx.x * 256 + threadIdx.x;
    if (t >= 4 * 9 * 8 * 64) return;
    const int d    = t / 4608;
    const int r    = t % 4608;
    const int ks   = r / 512;
    const int nt   = (r % 512) / 64;
    const int lane = r % 64;
    const float* Wd = (d == 0) ? W1 : (d == 1) ? W2 : (d == 2) ? W3 : W4;
    const int col = nt * 16 + (lane & 15);
    short8 v;
    #pragma unroll
    for (int j = 0; j < 8; ++j) {
        const int k = ks * 32 + ((lane >> 4) << 3) + j;
        float w = 0.f;
        if (k < 144)      w = Wd[k * 128 + col];
        else if (k < 272) w = Wself[(k - 144) * 128 + col];
        v[j] = (short)f2bf(w);
    }
    *reinterpret_cast<short8*>(packed + (size_t)d * SEG_ELEMS
                               + ((size_t)(ks * 8 + nt) * 64 + lane) * 8) = v;
}

// ---------------------------------------------------------------------------
// Block loop: 8 waves share one 32-row A tile; wave wv owns cols [16wv,16wv+16).
// B fragments live in registers (loaded ONCE per kernel: 9 x short8 = 36 VGPR).
// A K-layout: [a_sum 0..127 | b_sum 128..143 | self 144..271 | pad 272..287].
// ---------------------------------------------------------------------------
template <int DEG>
__device__ __forceinline__ void block_loop(
    const float* __restrict__ atom, const float* __restrict__ bond,
    const int* __restrict__ aidx, const int* __restrict__ bidx,
    const unsigned short* __restrict__ pw,
    float* __restrict__ out,
    unsigned short* __restrict__ A, int* __restrict__ own_lds,
    int n, int lb, int nb, int tid, int lane, int wv)
{
    const int m    = tid >> 4;           // node row 0..31 (block-wide gather)
    const int q16  = tid & 15;           // 8-float k-slice
    const int ccol = lane & 15;          // C col within 16-tile / A frag row
    const int crow = lane >> 4;          // C row group 0..3
    const int nbase = wv * 16;

    // ---- B fragments once per kernel ----
    short8 bfr[9];
    #pragma unroll
    for (int ks = 0; ks < 9; ++ks)
        bfr[ks] = ((const short8*)pw)[(ks * 8 + wv) * 64 + lane];

    float psum = 0.f, psq = 0.f;
    const int tiles = (n + 31) >> 5;

    for (int t = lb; t < tiles; t += nb) {
        const int i0 = t << 5;
        const int i = i0 + m;

        // ---- gather: 32 nodes x 16 slices across 512 threads ----
        if (i < n) {
            const int* ar = aidx + (size_t)i * (DEG + 1);
            const int own = ar[0];
            if (q16 == 0) own_lds[m] = own;
            const float4* s = (const float4*)(atom + (size_t)own * 128 + q16 * 8);
            float4 a0 = s[0], a1 = s[1];
            unsigned short* rowp = A + m * LDA;
            // self slice -> cols 144 + q16*8
            st_bf4(rowp + 144 + q16 * 8 + 0, a0);
            st_bf4(rowp + 144 + q16 * 8 + 4, a1);
            #pragma unroll
            for (int j = 1; j <= DEG; ++j) {
                const float4* p = (const float4*)(atom + (size_t)ar[j] * 128 + q16 * 8);
                a0 = add4(a0, p[0]); a1 = add4(a1, p[1]);
            }
            st_bf4(rowp + q16 * 8 + 0, a0);
            st_bf4(rowp + q16 * 8 + 4, a1);
            // bonds: threads q16<8 cover 2 of 16 cols each
            if (q16 < 8) {
                const int* br = bidx + (size_t)i * DEG;
                float bx = 0.f, by = 0.f;
                #pragma unroll
                for (int j = 0; j < DEG; ++j) {
                    const float2 bb = *(const float2*)(bond + (size_t)br[j] * 16 + q16 * 2);
                    bx += bb.x; by += bb.y;
                }
                unsigned short* pb = rowp + 128 + q16 * 2;
                pb[0] = f2bf(bx); pb[1] = f2bf(by);
            }
        }
        __syncthreads();

        // ---- MFMA: 32x288 @ 288x16 per wave, B already in registers ----
        floatx4 acc0 = (floatx4){0.f, 0.f, 0.f, 0.f};
        floatx4 acc1 = (floatx4){0.f, 0.f, 0.f, 0.f};
        #pragma unroll
        for (int ks = 0; ks < 9; ++ks) {
            const short8 af0 = *(const short8*)&A[ccol * LDA + ks * 32 + (crow << 3)];
            const short8 af1 = *(const short8*)&A[(16 + ccol) * LDA + ks * 32 + (crow << 3)];
            acc0 = __builtin_amdgcn_mfma_f32_16x16x32_bf16(af0, bfr[ks], acc0, 0, 0, 0);
            acc1 = __builtin_amdgcn_mfma_f32_16x16x32_bf16(af1, bfr[ks], acc1, 0, 0, 0);
        }

        // ---- scatter + BN partials ----
        const int4 o0 = *reinterpret_cast<const int4*>(&own_lds[crow * 4]);
        const int4 o1 = *reinterpret_cast<const int4*>(&own_lds[16 + crow * 4]);
        const int owns0[4] = {o0.x, o0.y, o0.z, o0.w};
        const int owns1[4] = {o1.x, o1.y, o1.z, o1.w};
        #pragma unroll
        for (int rr = 0; rr < 4; ++rr) {
            const int row = crow * 4 + rr;
            if (i0 + row < n) {
                const float v = acc0[rr];
                out[(size_t)owns0[rr] * 128 + nbase + ccol] = v;
                psum += v; psq += v * v;
            }
            if (i0 + 16 + row < n) {
                const float v = acc1[rr];
                out[(size_t)owns1[rr] * 128 + nbase + ccol] = v;
                psum += v; psq += v * v;
            }
        }
        __syncthreads();
    }

    // ---- per-block channel partials: waves own disjoint 16-col slices ----
    float* redS = reinterpret_cast<float*>(A);          // [128]
    float* redQ = redS + 128;                           // [128]
    {
        float s = psum, q = psq;
        s += __shfl_xor(s, 16, 64); s += __shfl_xor(s, 32, 64);
        q += __shfl_xor(q, 16, 64); q += __shfl_xor(q, 32, 64);
        if (lane < 16) {
            redS[nbase + lane] = s;
            redQ[nbase + lane] = q;
        }
    }
}

// ---------------------------------------------------------------------------
// Fused kernel: 512 threads = 8 waves; 19.5 KB LDS; natural VGPR (cap 128).
// ---------------------------------------------------------------------------
__global__ __launch_bounds__(512, 4) void gdc_mfma(
    const float* __restrict__ atom, const float* __restrict__ bond,
    const int* __restrict__ a1, const int* __restrict__ b1,
    const int* __restrict__ a2, const int* __restrict__ b2,
    const int* __restrict__ a3, const int* __restrict__ b3,
    const int* __restrict__ a4, const int* __restrict__ b4,
    const unsigned short* __restrict__ packedW,
    float* __restrict__ out,
    float* __restrict__ sumPart, float* __restrict__ sqPart)
{
    __shared__ __align__(16) unsigned short A[32 * LDA];   // 18944 B
    __shared__ __align__(16) int own_lds[32];

    const int tid  = threadIdx.x;
    const int wv   = tid >> 6;
    const int lane = tid & 63;
    const int blk  = blockIdx.x;

    int n, lb, nb, deg;
    const int* aidx; const int* bidx;
    if (blk < NB1)                 { deg = 1; n =  50000; lb = blk;                 nb = NB1; aidx = a1; bidx = b1; }
    else if (blk < NB1+NB2)        { deg = 2; n = 150000; lb = blk-NB1;             nb = NB2; aidx = a2; bidx = b2; }
    else if (blk < NB1+NB2+NB3)    { deg = 3; n = 200000; lb = blk-(NB1+NB2);       nb = NB3; aidx = a3; bidx = b3; }
    else                           { deg = 4; n = 100000; lb = blk-(NB1+NB2+NB3);   nb = NB4; aidx = a4; bidx = b4; }

    const unsigned short* pw = packedW + (size_t)(deg - 1) * SEG_ELEMS;

    // zero K-pad cols 272..287 once (never overwritten afterwards)
    {
        const int mm = tid >> 4, qq = tid & 15;
        if (qq >= 8) {
            ushort2 z; z.x = 0; z.y = 0;
            *reinterpret_cast<ushort2*>(&A[mm * LDA + 272 + (qq - 8) * 2]) = z;
        }
    }
    __syncthreads();

    switch (deg) {
    case 1:  block_loop<1>(atom, bond, aidx, bidx, pw, out, A, own_lds, n, lb, nb, tid, lane, wv); break;
    case 2:  block_loop<2>(atom, bond, aidx, bidx, pw, out, A, own_lds, n, lb, nb, tid, lane, wv); break;
    case 3:  block_loop<3>(atom, bond, aidx, bidx, pw, out, A, own_lds, n, lb, nb, tid, lane, wv); break;
    default: block_loop<4>(atom, bond, aidx, bidx, pw, out, A, own_lds, n, lb, nb, tid, lane, wv); break;
    }

    __syncthreads();
    const float* redS = reinterpret_cast<const float*>(A);
    if (tid < 128)      sumPart[(size_t)blk * 128 + tid] = redS[tid];
    else if (tid < 256) sqPart[(size_t)blk * 128 + (tid - 128)] = redS[tid];
}

// ---------------------------------------------------------------------------
// Reduce NBLK partials per channel -> mean, invstd (deterministic).
// ---------------------------------------------------------------------------
__global__ void gdc_stats(const float* __restrict__ sumPart,
                          const float* __restrict__ sqPart,
                          float* __restrict__ mv)
{
    const int c = blockIdx.x;
    const int j = threadIdx.x;
    __shared__ float rs[256], rq[256];
    float s = 0.f, q = 0.f;
    for (int b = j; b < NBLK; b += 256) {
        s += sumPart[(size_t)b * 128 + c];
        q += sqPart[(size_t)b * 128 + c];
    }
    rs[j] = s; rq[j] = q;
    __syncthreads();
    for (int off = 128; off > 0; off >>= 1) {
        if (j < off) { rs[j] += rs[j + off]; rq[j] += rq[j + off]; }
        __syncthreads();
    }
    if (j == 0) {
        const float mean = rs[0] / (float)N_ATOMS;
        const float var  = rq[0] / (float)N_ATOMS - mean * mean;
        mv[c]       = mean;
        mv[128 + c] = rsqrtf(var + EPS);
    }
}

// ---------------------------------------------------------------------------
// In-place normalize + ReLU. float4; per-thread channel loop-invariant.
// ---------------------------------------------------------------------------
__global__ __launch_bounds__(256) void gdc_norm(float* __restrict__ out,
                                                const float* __restrict__ mv)
{
    const size_t total4 = (size_t)N_ATOMS * 128 / 4;
    size_t idx = (size_t)blockIdx.x * 256 + threadIdx.x;
    const int c = (int)((idx * 4) & 127);
    const float4 m  = *(const float4*)(mv + c);
    const float4 iv = *(const float4*)(mv + 128 + c);
    const size_t stride = (size_t)gridDim.x * 256;
    for (; idx < total4; idx += stride) {
        float4 v = ((float4*)out)[idx];
        v.x = fmaxf(0.f, (v.x - m.x) * iv.x);
        v.y = fmaxf(0.f, (v.y - m.y) * iv.y);
        v.z = fmaxf(0.f, (v.z - m.z) * iv.z);
        v.w = fmaxf(0.f, (v.w - m.w) * iv.w);
        ((float4*)out)[idx] = v;
    }
}

extern "C" void kernel_launch(void* const* d_in, const int* in_sizes, int n_in,
                              void* d_out, int out_size, void* d_ws, size_t ws_size,
                              hipStream_t stream) {
    const float* atom  = (const float*)d_in[0];
    const float* bond  = (const float*)d_in[1];
    const int*   a1    = (const int*)d_in[2];
    const int*   b1    = (const int*)d_in[3];
    const int*   a2    = (const int*)d_in[4];
    const int*   b2    = (const int*)d_in[5];
    const int*   a3    = (const int*)d_in[6];
    const int*   b3    = (const int*)d_in[7];
    const int*   a4    = (const int*)d_in[8];
    const int*   b4    = (const int*)d_in[9];
    const float* Wself = (const float*)d_in[10];
    const float* W1    = (const float*)d_in[11];
    const float* W2    = (const float*)d_in[12];
    const float* W3    = (const float*)d_in[13];
    const float* W4    = (const float*)d_in[14];
    // bias cancels under BatchNorm (shift-invariance; verified R5/R6) -> unused
    float* out = (float*)d_out;

    // ws layout: packedW (294912 B) | sumPart[NBLK*128] | sqPart[NBLK*128] | mv[256]
    unsigned short* packedW = (unsigned short*)d_ws;
    float* sumPart = (float*)((char*)d_ws + 4 * SEG_ELEMS * sizeof(unsigned short));
    float* sqPart  = sumPart + (size_t)NBLK * 128;
    float* mv      = sqPart + (size_t)NBLK * 128;

    hipLaunchKernelGGL(gdc_pack, dim3((4*9*8*64 + 255)/256), dim3(256), 0, stream,
                       W1, W2, W3, W4, Wself, packedW);
    hipLaunchKernelGGL(gdc_mfma, dim3(NBLK), dim3(512), 0, stream,
                       atom, bond, a1, b1, a2, b2, a3, b3, a4, b4,
                       packedW, out, sumPart, sqPart);
    hipLaunchKernelGGL(gdc_stats, dim3(128), dim3(256), 0, stream,
                       sumPart, sqPart, mv);
    hipLaunchKernelGGL(gdc_norm, dim3(2048), dim3(256), 0, stream, out, mv);
}

// Round 11
// 340.019 us; speedup vs baseline: 1.6870x; 1.0350x over previous
//
#include <hip/hip_runtime.h>
#include <hip/hip_bf16.h>
#include <math.h>

#define N_ATOMS 500000
#define EPS 1e-5f
#define LDA 296   // bf16 elems per A row: 288 + 8 pad

// blocks per degree segment (1024 blocks), proportional to gather volume n_d*(d+1)
#define NB1 55
#define NB2 249
#define NB3 443
#define NB4 277
#define NBLK 1024

#define SEG_ELEMS 36864   // 288*128 bf16 per packed weight segment

typedef __attribute__((ext_vector_type(8))) short short8;
typedef __attribute__((ext_vector_type(4))) float floatx4;

__device__ __forceinline__ unsigned short f2bf(float f) {
    unsigned int x = __float_as_uint(f);
    x += 0x7FFF + ((x >> 16) & 1);          // round-to-nearest-even
    return (unsigned short)(x >> 16);
}

__device__ __forceinline__ float4 add4(float4 a, float4 b) {
    return make_float4(a.x + b.x, a.y + b.y, a.z + b.z, a.w + b.w);
}

__device__ __forceinline__ void st_bf4(unsigned short* p, float4 v) {
    ushort4 u;
    u.x = f2bf(v.x); u.y = f2bf(v.y); u.z = f2bf(v.z); u.w = f2bf(v.w);
    *reinterpret_cast<ushort4*>(p) = u;     // ds_write_b64
}

// ---------------------------------------------------------------------------
// Pack weights into MFMA B-fragment layout, bf16.
// packed[d]: (ks 0..8, nt 0..7, lane 0..63) -> short8; col = nt*16+(lane&15),
// k = ks*32 + (lane>>4)*8 + j; k<144 -> W_d rows, k<272 -> W_self, else 0.
// ---------------------------------------------------------------------------
__global__ __launch_bounds__(256) void gdc_pack(
    const float* __restrict__ W1, const float* __restrict__ W2,
    const float* __restrict__ W3, const float* __restrict__ W4,
    const float* __restrict__ Wself, unsigned short* __restrict__ packed)
{
    const int t = blockIdx.x * 256 + threadIdx.x;
    if (t >= 4 * 9 * 8 * 64) return;
    const int d    = t / 4608;
    const int r    = t % 4608;
    const int ks   = r / 512;
    const int nt   = (r % 512) / 64;
    const int lane = r % 64;
    const float* Wd = (d == 0) ? W1 : (d == 1) ? W2 : (d == 2) ? W3 : W4;
    const int col = nt * 16 + (lane & 15);
    short8 v;
    #pragma unroll
    for (int j = 0; j < 8; ++j) {
        const int k = ks * 32 + ((lane >> 4) << 3) + j;
        float w = 0.f;
        if (k < 144)      w = Wd[k * 128 + col];
        else if (k < 272) w = Wself[(k - 144) * 128 + col];
        v[j] = (short)f2bf(w);
    }
    *reinterpret_cast<short8*>(packed + (size_t)d * SEG_ELEMS
                               + ((size_t)(ks * 8 + nt) * 64 + lane) * 8) = v;
}

// ---------------------------------------------------------------------------
// Pipelined block loop: 8 waves, wave wv owns cols [16wv,16wv+16).
// Double-buffered 32-row A tile; one barrier per tile.
// Per iteration: commit regs->LDS | barrier | issue next gather | MFMA+scatter.
// Indices prefetched one extra tile ahead so gathers issue immediately.
// ---------------------------------------------------------------------------
template <int DEG>
__device__ __forceinline__ void block_loop(
    const float* __restrict__ atom, const float* __restrict__ bond,
    const int* __restrict__ aidx, const int* __restrict__ bidx,
    const unsigned short* __restrict__ pw,
    float* __restrict__ out,
    unsigned short* __restrict__ A, int* __restrict__ own_lds,
    int n, int lb, int nb, int tid, int lane, int wv)
{
    const int m    = tid >> 4;           // node row 0..31
    const int q16  = tid & 15;           // 8-float k-slice
    const int ccol = lane & 15;
    const int crow = lane >> 4;
    const int nbase = wv * 16;

    // ---- B fragments once per kernel (9 x short8 = 36 VGPR) ----
    short8 bfr[9];
    #pragma unroll
    for (int ks = 0; ks < 9; ++ks)
        bfr[ks] = ((const short8*)pw)[(ks * 8 + wv) * 64 + lane];

    float psum = 0.f, psq = 0.f;
    const int tiles = (n + 31) >> 5;
    const int nmax  = n - 1;

    // ---- prologue: gather tile lb; prefetch idx row of tile lb+nb ----
    float4 self0, self1, sum0, sum1;
    float bx, by;
    int own_r;
    int ni[DEG + 1];
    {
        const int i = min((lb << 5) + m, nmax);
        const int* ar = aidx + (size_t)i * (DEG + 1);
        #pragma unroll
        for (int j = 0; j <= DEG; ++j) ni[j] = ar[j];
        own_r = ni[0];
        const float4* s = (const float4*)(atom + (size_t)own_r * 128 + q16 * 8);
        self0 = s[0]; self1 = s[1];
        sum0 = self0; sum1 = self1;
        #pragma unroll
        for (int j = 1; j <= DEG; ++j) {
            const float4* pp = (const float4*)(atom + (size_t)ni[j] * 128 + q16 * 8);
            sum0 = add4(sum0, pp[0]); sum1 = add4(sum1, pp[1]);
        }
        bx = 0.f; by = 0.f;
        if (q16 < 8) {
            const int* br = bidx + (size_t)i * DEG;
            #pragma unroll
            for (int j = 0; j < DEG; ++j) {
                const float2 bb = *(const float2*)(bond + (size_t)br[j] * 16 + q16 * 2);
                bx += bb.x; by += bb.y;
            }
        }
        const int t1 = min(lb + nb, tiles - 1);
        const int i1 = min((t1 << 5) + m, nmax);
        const int* ar1 = aidx + (size_t)i1 * (DEG + 1);
        #pragma unroll
        for (int j = 0; j <= DEG; ++j) ni[j] = ar1[j];
    }

    int k = 0;
    for (int t = lb; t < tiles; t += nb, ++k) {
        unsigned short* Ab = A + (k & 1) * (32 * LDA);
        int* ob = own_lds + (k & 1) * 32;

        // ---- commit tile t: regs -> LDS ----
        {
            unsigned short* rowp = Ab + m * LDA;
            st_bf4(rowp + 144 + q16 * 8 + 0, self0);
            st_bf4(rowp + 144 + q16 * 8 + 4, self1);
            st_bf4(rowp + q16 * 8 + 0, sum0);
            st_bf4(rowp + q16 * 8 + 4, sum1);
            if (q16 < 8) {
                rowp[128 + q16 * 2]     = f2bf(bx);
                rowp[128 + q16 * 2 + 1] = f2bf(by);
            }
            if (q16 == 0) ob[m] = own_r;
        }
        __syncthreads();

        // ---- issue gather for tile t+nb (block-uniform branch) ----
        if (t + nb < tiles) {
            const int i = min(((t + nb) << 5) + m, nmax);
            own_r = ni[0];
            const float4* s = (const float4*)(atom + (size_t)own_r * 128 + q16 * 8);
            self0 = s[0]; self1 = s[1];
            float4 ns0 = self0, ns1 = self1;
            #pragma unroll
            for (int j = 1; j <= DEG; ++j) {
                const float4* pp = (const float4*)(atom + (size_t)ni[j] * 128 + q16 * 8);
                ns0 = add4(ns0, pp[0]); ns1 = add4(ns1, pp[1]);
            }
            sum0 = ns0; sum1 = ns1;
            bx = 0.f; by = 0.f;
            if (q16 < 8) {
                const int* br = bidx + (size_t)i * DEG;
                #pragma unroll
                for (int j = 0; j < DEG; ++j) {
                    const float2 bb = *(const float2*)(bond + (size_t)br[j] * 16 + q16 * 2);
                    bx += bb.x; by += bb.y;
                }
            }
            const int t2 = min(t + 2 * nb, tiles - 1);
            const int i2 = min((t2 << 5) + m, nmax);
            const int* ar2 = aidx + (size_t)i2 * (DEG + 1);
            #pragma unroll
            for (int j = 0; j <= DEG; ++j) ni[j] = ar2[j];
        }

        // ---- MFMA tile t (loads above overlap this) ----
        floatx4 acc0 = (floatx4){0.f, 0.f, 0.f, 0.f};
        floatx4 acc1 = (floatx4){0.f, 0.f, 0.f, 0.f};
        #pragma unroll
        for (int ks = 0; ks < 9; ++ks) {
            const short8 af0 = *(const short8*)&Ab[ccol * LDA + ks * 32 + (crow << 3)];
            const short8 af1 = *(const short8*)&Ab[(16 + ccol) * LDA + ks * 32 + (crow << 3)];
            acc0 = __builtin_amdgcn_mfma_f32_16x16x32_bf16(af0, bfr[ks], acc0, 0, 0, 0);
            acc1 = __builtin_amdgcn_mfma_f32_16x16x32_bf16(af1, bfr[ks], acc1, 0, 0, 0);
        }

        // ---- scatter + BN partials ----
        const int i0 = t << 5;
        const int4 o0 = *reinterpret_cast<const int4*>(&ob[crow * 4]);
        const int4 o1 = *reinterpret_cast<const int4*>(&ob[16 + crow * 4]);
        const int owns0[4] = {o0.x, o0.y, o0.z, o0.w};
        const int owns1[4] = {o1.x, o1.y, o1.z, o1.w};
        #pragma unroll
        for (int rr = 0; rr < 4; ++rr) {
            const int row = crow * 4 + rr;
            if (i0 + row < n) {
                const float v = acc0[rr];
                out[(size_t)owns0[rr] * 128 + nbase + ccol] = v;
                psum += v; psq += v * v;
            }
            if (i0 + 16 + row < n) {
                const float v = acc1[rr];
                out[(size_t)owns1[rr] * 128 + nbase + ccol] = v;
                psum += v; psq += v * v;
            }
        }
    }

    __syncthreads();   // all waves done with LDS before aliasing it

    // ---- per-block channel partials: waves own disjoint 16-col slices ----
    float* redS = reinterpret_cast<float*>(A);          // [128]
    float* redQ = redS + 128;                           // [128]
    {
        float s = psum, q = psq;
        s += __shfl_xor(s, 16, 64); s += __shfl_xor(s, 32, 64);
        q += __shfl_xor(q, 16, 64); q += __shfl_xor(q, 32, 64);
        if (lane < 16) {
            redS[nbase + lane] = s;
            redQ[nbase + lane] = q;
        }
    }
}

// ---------------------------------------------------------------------------
// Fused kernel: 512 threads = 8 waves; 38.1 KB LDS (double-buffered A).
// ---------------------------------------------------------------------------
__global__ __launch_bounds__(512, 4) void gdc_mfma(
    const float* __restrict__ atom, const float* __restrict__ bond,
    const int* __restrict__ a1, const int* __restrict__ b1,
    const int* __restrict__ a2, const int* __restrict__ b2,
    const int* __restrict__ a3, const int* __restrict__ b3,
    const int* __restrict__ a4, const int* __restrict__ b4,
    const unsigned short* __restrict__ packedW,
    float* __restrict__ out,
    float* __restrict__ sumPart, float* __restrict__ sqPart)
{
    __shared__ __align__(16) unsigned short A[2 * 32 * LDA];   // 37888 B
    __shared__ __align__(16) int own_lds[2 * 32];

    const int tid  = threadIdx.x;
    const int wv   = tid >> 6;
    const int lane = tid & 63;
    const int blk  = blockIdx.x;

    int n, lb, nb, deg;
    const int* aidx; const int* bidx;
    if (blk < NB1)                 { deg = 1; n =  50000; lb = blk;                 nb = NB1; aidx = a1; bidx = b1; }
    else if (blk < NB1+NB2)        { deg = 2; n = 150000; lb = blk-NB1;             nb = NB2; aidx = a2; bidx = b2; }
    else if (blk < NB1+NB2+NB3)    { deg = 3; n = 200000; lb = blk-(NB1+NB2);       nb = NB3; aidx = a3; bidx = b3; }
    else                           { deg = 4; n = 100000; lb = blk-(NB1+NB2+NB3);   nb = NB4; aidx = a4; bidx = b4; }

    const unsigned short* pw = packedW + (size_t)(deg - 1) * SEG_ELEMS;

    // zero K-pad cols 272..287 of both buffers once
    {
        const int mm = tid >> 4, qq = tid & 15;
        if (qq >= 8) {
            ushort2 z; z.x = 0; z.y = 0;
            *reinterpret_cast<ushort2*>(&A[mm * LDA + 272 + (qq - 8) * 2]) = z;
            *reinterpret_cast<ushort2*>(&A[32 * LDA + mm * LDA + 272 + (qq - 8) * 2]) = z;
        }
    }
    __syncthreads();

    switch (deg) {
    case 1:  block_loop<1>(atom, bond, aidx, bidx, pw, out, A, own_lds, n, lb, nb, tid, lane, wv); break;
    case 2:  block_loop<2>(atom, bond, aidx, bidx, pw, out, A, own_lds, n, lb, nb, tid, lane, wv); break;
    case 3:  block_loop<3>(atom, bond, aidx, bidx, pw, out, A, own_lds, n, lb, nb, tid, lane, wv); break;
    default: block_loop<4>(atom, bond, aidx, bidx, pw, out, A, own_lds, n, lb, nb, tid, lane, wv); break;
    }

    __syncthreads();
    const float* redS = reinterpret_cast<const float*>(A);
    if (tid < 128)      sumPart[(size_t)blk * 128 + tid] = redS[tid];
    else if (tid < 256) sqPart[(size_t)blk * 128 + (tid - 128)] = redS[tid];
}

// ---------------------------------------------------------------------------
// Reduce NBLK partials per channel -> mean, invstd (deterministic).
// ---------------------------------------------------------------------------
__global__ void gdc_stats(const float* __restrict__ sumPart,
                          const float* __restrict__ sqPart,
                          float* __restrict__ mv)
{
    const int c = blockIdx.x;
    const int j = threadIdx.x;
    __shared__ float rs[256], rq[256];
    float s = 0.f, q = 0.f;
    for (int b = j; b < NBLK; b += 256) {
        s += sumPart[(size_t)b * 128 + c];
        q += sqPart[(size_t)b * 128 + c];
    }
    rs[j] = s; rq[j] = q;
    __syncthreads();
    for (int off = 128; off > 0; off >>= 1) {
        if (j < off) { rs[j] += rs[j + off]; rq[j] += rq[j + off]; }
        __syncthreads();
    }
    if (j == 0) {
        const float mean = rs[0] / (float)N_ATOMS;
        const float var  = rq[0] / (float)N_ATOMS - mean * mean;
        mv[c]       = mean;
        mv[128 + c] = rsqrtf(var + EPS);
    }
}

// ---------------------------------------------------------------------------
// In-place normalize + ReLU. float4; per-thread channel loop-invariant.
// ---------------------------------------------------------------------------
__global__ __launch_bounds__(256) void gdc_norm(float* __restrict__ out,
                                                const float* __restrict__ mv)
{
    const size_t total4 = (size_t)N_ATOMS * 128 / 4;
    size_t idx = (size_t)blockIdx.x * 256 + threadIdx.x;
    const int c = (int)((idx * 4) & 127);
    const float4 m  = *(const float4*)(mv + c);
    const float4 iv = *(const float4*)(mv + 128 + c);
    const size_t stride = (size_t)gridDim.x * 256;
    for (; idx < total4; idx += stride) {
        float4 v = ((float4*)out)[idx];
        v.x = fmaxf(0.f, (v.x - m.x) * iv.x);
        v.y = fmaxf(0.f, (v.y - m.y) * iv.y);
        v.z = fmaxf(0.f, (v.z - m.z) * iv.z);
        v.w = fmaxf(0.f, (v.w - m.w) * iv.w);
        ((float4*)out)[idx] = v;
    }
}

extern "C" void kernel_launch(void* const* d_in, const int* in_sizes, int n_in,
                              void* d_out, int out_size, void* d_ws, size_t ws_size,
                              hipStream_t stream) {
    const float* atom  = (const float*)d_in[0];
    const float* bond  = (const float*)d_in[1];
    const int*   a1    = (const int*)d_in[2];
    const int*   b1    = (const int*)d_in[3];
    const int*   a2    = (const int*)d_in[4];
    const int*   b2    = (const int*)d_in[5];
    const int*   a3    = (const int*)d_in[6];
    const int*   b3    = (const int*)d_in[7];
    const int*   a4    = (const int*)d_in[8];
    const int*   b4    = (const int*)d_in[9];
    const float* Wself = (const float*)d_in[10];
    const float* W1    = (const float*)d_in[11];
    const float* W2    = (const float*)d_in[12];
    const float* W3    = (const float*)d_in[13];
    const float* W4    = (const float*)d_in[14];
    // bias cancels under BatchNorm (shift-invariance; verified R5/R6) -> unused
    float* out = (float*)d_out;

    // ws layout: packedW (294912 B) | sumPart[NBLK*128] | sqPart[NBLK*128] | mv[256]
    unsigned short* packedW = (unsigned short*)d_ws;
    float* sumPart = (float*)((char*)d_ws + 4 * SEG_ELEMS * sizeof(unsigned short));
    float* sqPart  = sumPart + (size_t)NBLK * 128;
    float* mv      = sqPart + (size_t)NBLK * 128;

    hipLaunchKernelGGL(gdc_pack, dim3((4*9*8*64 + 255)/256), dim3(256), 0, stream,
                       W1, W2, W3, W4, Wself, packedW);
    hipLaunchKernelGGL(gdc_mfma, dim3(NBLK), dim3(512), 0, stream,
                       atom, bond, a1, b1, a2, b2, a3, b3, a4, b4,
                       packedW, out, sumPart, sqPart);
    hipLaunchKernelGGL(gdc_stats, dim3(128), dim3(256), 0, stream,
                       sumPart, sqPart, mv);
    hipLaunchKernelGGL(gdc_norm, dim3(2048), dim3(256), 0, stream, out, mv);
}

// Round 13
// 330.420 us; speedup vs baseline: 1.7360x; 1.0291x over previous
//
#include <hip/hip_runtime.h>
#include <hip/hip_bf16.h>
#include <math.h>

#define N_ATOMS 500000
#define EPS 1e-5f
#define LDA 296   // bf16 elems per A row: 288 + 8 pad

// blocks per degree segment (1024 blocks), proportional to gather volume n_d*(d+1)
#define NB1 55
#define NB2 249
#define NB3 443
#define NB4 277
#define NBLK 1024

#define SEG_ELEMS 36864   // 288*128 bf16 per packed weight segment

typedef __attribute__((ext_vector_type(8))) short short8;
typedef __attribute__((ext_vector_type(4))) float floatx4;

__device__ __forceinline__ unsigned short f2bf(float f) {
    unsigned int x = __float_as_uint(f);
    x += 0x7FFF + ((x >> 16) & 1);          // round-to-nearest-even
    return (unsigned short)(x >> 16);
}

__device__ __forceinline__ float4 add4(float4 a, float4 b) {
    return make_float4(a.x + b.x, a.y + b.y, a.z + b.z, a.w + b.w);
}

__device__ __forceinline__ void st_bf4(unsigned short* p, float4 v) {
    ushort4 u;
    u.x = f2bf(v.x); u.y = f2bf(v.y); u.z = f2bf(v.z); u.w = f2bf(v.w);
    *reinterpret_cast<ushort4*>(p) = u;     // ds_write_b64
}

// ---------------------------------------------------------------------------
// Pack weights into MFMA B-fragment layout, bf16.
// packed[d]: (ks 0..8, nt 0..7, lane 0..63) -> short8; col = nt*16+(lane&15),
// k = ks*32 + (lane>>4)*8 + j; k<144 -> W_d rows, k<272 -> W_self, else 0.
// ---------------------------------------------------------------------------
__global__ __launch_bounds__(256) void gdc_pack(
    const float* __restrict__ W1, const float* __restrict__ W2,
    const float* __restrict__ W3, const float* __restrict__ W4,
    const float* __restrict__ Wself, unsigned short* __restrict__ packed)
{
    const int t = blockIdx.x * 256 + threadIdx.x;
    if (t >= 4 * 9 * 8 * 64) return;
    const int d    = t / 4608;
    const int r    = t % 4608;
    const int ks   = r / 512;
    const int nt   = (r % 512) / 64;
    const int lane = r % 64;
    const float* Wd = (d == 0) ? W1 : (d == 1) ? W2 : (d == 2) ? W3 : W4;
    const int col = nt * 16 + (lane & 15);
    short8 v;
    #pragma unroll
    for (int j = 0; j < 8; ++j) {
        const int k = ks * 32 + ((lane >> 4) << 3) + j;
        float w = 0.f;
        if (k < 144)      w = Wd[k * 128 + col];
        else if (k < 272) w = Wself[(k - 144) * 128 + col];
        v[j] = (short)f2bf(w);
    }
    *reinterpret_cast<short8*>(packed + (size_t)d * SEG_ELEMS
                               + ((size_t)(ks * 8 + nt) * 64 + lane) * 8) = v;
}

// ---------------------------------------------------------------------------
// Pipelined block loop: 8 waves, wave wv owns cols [16wv,16wv+16).
// Double-buffered 32-row A tile; one barrier per tile.
// out-stores are NON-TEMPORAL: keep L3 for the 256MB atom table (gathers).
// ---------------------------------------------------------------------------
template <int DEG>
__device__ __forceinline__ void block_loop(
    const float* __restrict__ atom, const float* __restrict__ bond,
    const int* __restrict__ aidx, const int* __restrict__ bidx,
    const unsigned short* __restrict__ pw,
    float* __restrict__ out,
    unsigned short* __restrict__ A, int* __restrict__ own_lds,
    int n, int lb, int nb, int tid, int lane, int wv)
{
    const int m    = tid >> 4;           // node row 0..31
    const int q16  = tid & 15;           // 8-float k-slice
    const int ccol = lane & 15;
    const int crow = lane >> 4;
    const int nbase = wv * 16;

    // ---- B fragments once per kernel (9 x short8 = 36 VGPR) ----
    short8 bfr[9];
    #pragma unroll
    for (int ks = 0; ks < 9; ++ks)
        bfr[ks] = ((const short8*)pw)[(ks * 8 + wv) * 64 + lane];

    float psum = 0.f, psq = 0.f;
    const int tiles = (n + 31) >> 5;
    const int nmax  = n - 1;

    // ---- prologue: gather tile lb; prefetch idx row of tile lb+nb ----
    float4 self0, self1, sum0, sum1;
    float bx, by;
    int own_r;
    int ni[DEG + 1];
    {
        const int i = min((lb << 5) + m, nmax);
        const int* ar = aidx + (size_t)i * (DEG + 1);
        #pragma unroll
        for (int j = 0; j <= DEG; ++j) ni[j] = ar[j];
        own_r = ni[0];
        const float4* s = (const float4*)(atom + (size_t)own_r * 128 + q16 * 8);
        self0 = s[0]; self1 = s[1];
        sum0 = self0; sum1 = self1;
        #pragma unroll
        for (int j = 1; j <= DEG; ++j) {
            const float4* pp = (const float4*)(atom + (size_t)ni[j] * 128 + q16 * 8);
            sum0 = add4(sum0, pp[0]); sum1 = add4(sum1, pp[1]);
        }
        bx = 0.f; by = 0.f;
        if (q16 < 8) {
            const int* br = bidx + (size_t)i * DEG;
            #pragma unroll
            for (int j = 0; j < DEG; ++j) {
                const float2 bb = *(const float2*)(bond + (size_t)br[j] * 16 + q16 * 2);
                bx += bb.x; by += bb.y;
            }
        }
        const int t1 = min(lb + nb, tiles - 1);
        const int i1 = min((t1 << 5) + m, nmax);
        const int* ar1 = aidx + (size_t)i1 * (DEG + 1);
        #pragma unroll
        for (int j = 0; j <= DEG; ++j) ni[j] = ar1[j];
    }

    int k = 0;
    for (int t = lb; t < tiles; t += nb, ++k) {
        unsigned short* Ab = A + (k & 1) * (32 * LDA);
        int* ob = own_lds + (k & 1) * 32;

        // ---- commit tile t: regs -> LDS ----
        {
            unsigned short* rowp = Ab + m * LDA;
            st_bf4(rowp + 144 + q16 * 8 + 0, self0);
            st_bf4(rowp + 144 + q16 * 8 + 4, self1);
            st_bf4(rowp + q16 * 8 + 0, sum0);
            st_bf4(rowp + q16 * 8 + 4, sum1);
            if (q16 < 8) {
                rowp[128 + q16 * 2]     = f2bf(bx);
                rowp[128 + q16 * 2 + 1] = f2bf(by);
            }
            if (q16 == 0) ob[m] = own_r;
        }
        __syncthreads();

        // ---- issue gather for tile t+nb (block-uniform branch) ----
        if (t + nb < tiles) {
            const int i = min(((t + nb) << 5) + m, nmax);
            own_r = ni[0];
            const float4* s = (const float4*)(atom + (size_t)own_r * 128 + q16 * 8);
            self0 = s[0]; self1 = s[1];
            float4 ns0 = self0, ns1 = self1;
            #pragma unroll
            for (int j = 1; j <= DEG; ++j) {
                const float4* pp = (const float4*)(atom + (size_t)ni[j] * 128 + q16 * 8);
                ns0 = add4(ns0, pp[0]); ns1 = add4(ns1, pp[1]);
            }
            sum0 = ns0; sum1 = ns1;
            bx = 0.f; by = 0.f;
            if (q16 < 8) {
                const int* br = bidx + (size_t)i * DEG;
                #pragma unroll
                for (int j = 0; j < DEG; ++j) {
                    const float2 bb = *(const float2*)(bond + (size_t)br[j] * 16 + q16 * 2);
                    bx += bb.x; by += bb.y;
                }
            }
            const int t2 = min(t + 2 * nb, tiles - 1);
            const int i2 = min((t2 << 5) + m, nmax);
            const int* ar2 = aidx + (size_t)i2 * (DEG + 1);
            #pragma unroll
            for (int j = 0; j <= DEG; ++j) ni[j] = ar2[j];
        }

        // ---- MFMA tile t (loads above overlap this) ----
        floatx4 acc0 = (floatx4){0.f, 0.f, 0.f, 0.f};
        floatx4 acc1 = (floatx4){0.f, 0.f, 0.f, 0.f};
        #pragma unroll
        for (int ks = 0; ks < 9; ++ks) {
            const short8 af0 = *(const short8*)&Ab[ccol * LDA + ks * 32 + (crow << 3)];
            const short8 af1 = *(const short8*)&Ab[(16 + ccol) * LDA + ks * 32 + (crow << 3)];
            acc0 = __builtin_amdgcn_mfma_f32_16x16x32_bf16(af0, bfr[ks], acc0, 0, 0, 0);
            acc1 = __builtin_amdgcn_mfma_f32_16x16x32_bf16(af1, bfr[ks], acc1, 0, 0, 0);
        }

        // ---- scatter (non-temporal) + BN partials ----
        const int i0 = t << 5;
        const int4 o0 = *reinterpret_cast<const int4*>(&ob[crow * 4]);
        const int4 o1 = *reinterpret_cast<const int4*>(&ob[16 + crow * 4]);
        const int owns0[4] = {o0.x, o0.y, o0.z, o0.w};
        const int owns1[4] = {o1.x, o1.y, o1.z, o1.w};
        #pragma unroll
        for (int rr = 0; rr < 4; ++rr) {
            const int row = crow * 4 + rr;
            if (i0 + row < n) {
                const float v = acc0[rr];
                __builtin_nontemporal_store(v, &out[(size_t)owns0[rr] * 128 + nbase + ccol]);
                psum += v; psq += v * v;
            }
            if (i0 + 16 + row < n) {
                const float v = acc1[rr];
                __builtin_nontemporal_store(v, &out[(size_t)owns1[rr] * 128 + nbase + ccol]);
                psum += v; psq += v * v;
            }
        }
    }

    __syncthreads();   // all waves done with LDS before aliasing it

    // ---- per-block channel partials: waves own disjoint 16-col slices ----
    float* redS = reinterpret_cast<float*>(A);          // [128]
    float* redQ = redS + 128;                           // [128]
    {
        float s = psum, q = psq;
        s += __shfl_xor(s, 16, 64); s += __shfl_xor(s, 32, 64);
        q += __shfl_xor(q, 16, 64); q += __shfl_xor(q, 32, 64);
        if (lane < 16) {
            redS[nbase + lane] = s;
            redQ[nbase + lane] = q;
        }
    }
}

// ---------------------------------------------------------------------------
// Fused kernel: 512 threads = 8 waves; 38.1 KB LDS (double-buffered A).
// ---------------------------------------------------------------------------
__global__ __launch_bounds__(512, 4) void gdc_mfma(
    const float* __restrict__ atom, const float* __restrict__ bond,
    const int* __restrict__ a1, const int* __restrict__ b1,
    const int* __restrict__ a2, const int* __restrict__ b2,
    const int* __restrict__ a3, const int* __restrict__ b3,
    const int* __restrict__ a4, const int* __restrict__ b4,
    const unsigned short* __restrict__ packedW,
    float* __restrict__ out,
    float* __restrict__ sumPart, float* __restrict__ sqPart)
{
    __shared__ __align__(16) unsigned short A[2 * 32 * LDA];   // 37888 B
    __shared__ __align__(16) int own_lds[2 * 32];

    const int tid  = threadIdx.x;
    const int wv   = tid >> 6;
    const int lane = tid & 63;
    const int blk  = blockIdx.x;

    int n, lb, nb, deg;
    const int* aidx; const int* bidx;
    if (blk < NB1)                 { deg = 1; n =  50000; lb = blk;                 nb = NB1; aidx = a1; bidx = b1; }
    else if (blk < NB1+NB2)        { deg = 2; n = 150000; lb = blk-NB1;             nb = NB2; aidx = a2; bidx = b2; }
    else if (blk < NB1+NB2+NB3)    { deg = 3; n = 200000; lb = blk-(NB1+NB2);       nb = NB3; aidx = a3; bidx = b3; }
    else                           { deg = 4; n = 100000; lb = blk-(NB1+NB2+NB3);   nb = NB4; aidx = a4; bidx = b4; }

    const unsigned short* pw = packedW + (size_t)(deg - 1) * SEG_ELEMS;

    // zero K-pad cols 272..287 of both buffers once
    {
        const int mm = tid >> 4, qq = tid & 15;
        if (qq >= 8) {
            ushort2 z; z.x = 0; z.y = 0;
            *reinterpret_cast<ushort2*>(&A[mm * LDA + 272 + (qq - 8) * 2]) = z;
            *reinterpret_cast<ushort2*>(&A[32 * LDA + mm * LDA + 272 + (qq - 8) * 2]) = z;
        }
    }
    __syncthreads();

    switch (deg) {
    case 1:  block_loop<1>(atom, bond, aidx, bidx, pw, out, A, own_lds, n, lb, nb, tid, lane, wv); break;
    case 2:  block_loop<2>(atom, bond, aidx, bidx, pw, out, A, own_lds, n, lb, nb, tid, lane, wv); break;
    case 3:  block_loop<3>(atom, bond, aidx, bidx, pw, out, A, own_lds, n, lb, nb, tid, lane, wv); break;
    default: block_loop<4>(atom, bond, aidx, bidx, pw, out, A, own_lds, n, lb, nb, tid, lane, wv); break;
    }

    __syncthreads();
    const float* redS = reinterpret_cast<const float*>(A);
    if (tid < 128)      sumPart[(size_t)blk * 128 + tid] = redS[tid];
    else if (tid < 256) sqPart[(size_t)blk * 128 + (tid - 128)] = redS[tid];
}

// ---------------------------------------------------------------------------
// Reduce NBLK partials per channel -> mean, invstd (deterministic).
// ---------------------------------------------------------------------------
__global__ void gdc_stats(const float* __restrict__ sumPart,
                          const float* __restrict__ sqPart,
                          float* __restrict__ mv)
{
    const int c = blockIdx.x;
    const int j = threadIdx.x;
    __shared__ float rs[256], rq[256];
    float s = 0.f, q = 0.f;
    for (int b = j; b < NBLK; b += 256) {
        s += sumPart[(size_t)b * 128 + c];
        q += sqPart[(size_t)b * 128 + c];
    }
    rs[j] = s; rq[j] = q;
    __syncthreads();
    for (int off = 128; off > 0; off >>= 1) {
        if (j < off) { rs[j] += rs[j + off]; rq[j] += rq[j + off]; }
        __syncthreads();
    }
    if (j == 0) {
        const float mean = rs[0] / (float)N_ATOMS;
        const float var  = rq[0] / (float)N_ATOMS - mean * mean;
        mv[c]       = mean;
        mv[128 + c] = rsqrtf(var + EPS);
    }
}

// ---------------------------------------------------------------------------
// In-place normalize + ReLU. Native-vector float4 non-temporal load/store.
// ---------------------------------------------------------------------------
__global__ __launch_bounds__(256) void gdc_norm(float* __restrict__ out,
                                                const float* __restrict__ mv)
{
    const size_t total4 = (size_t)N_ATOMS * 128 / 4;
    size_t idx = (size_t)blockIdx.x * 256 + threadIdx.x;
    const int c = (int)((idx * 4) & 127);
    const float4 m  = *(const float4*)(mv + c);
    const float4 iv = *(const float4*)(mv + 128 + c);
    const size_t stride = (size_t)gridDim.x * 256;
    for (; idx < total4; idx += stride) {
        floatx4 v = __builtin_nontemporal_load(((const floatx4*)out) + idx);
        v[0] = fmaxf(0.f, (v[0] - m.x) * iv.x);
        v[1] = fmaxf(0.f, (v[1] - m.y) * iv.y);
        v[2] = fmaxf(0.f, (v[2] - m.z) * iv.z);
        v[3] = fmaxf(0.f, (v[3] - m.w) * iv.w);
        __builtin_nontemporal_store(v, ((floatx4*)out) + idx);
    }
}

extern "C" void kernel_launch(void* const* d_in, const int* in_sizes, int n_in,
                              void* d_out, int out_size, void* d_ws, size_t ws_size,
                              hipStream_t stream) {
    const float* atom  = (const float*)d_in[0];
    const float* bond  = (const float*)d_in[1];
    const int*   a1    = (const int*)d_in[2];
    const int*   b1    = (const int*)d_in[3];
    const int*   a2    = (const int*)d_in[4];
    const int*   b2    = (const int*)d_in[5];
    const int*   a3    = (const int*)d_in[6];
    const int*   b3    = (const int*)d_in[7];
    const int*   a4    = (const int*)d_in[8];
    const int*   b4    = (const int*)d_in[9];
    const float* Wself = (const float*)d_in[10];
    const float* W1    = (const float*)d_in[11];
    const float* W2    = (const float*)d_in[12];
    const float* W3    = (const float*)d_in[13];
    const float* W4    = (const float*)d_in[14];
    // bias cancels under BatchNorm (shift-invariance; verified R5/R6) -> unused
    float* out = (float*)d_out;

    // ws layout: packedW (294912 B) | sumPart[NBLK*128] | sqPart[NBLK*128] | mv[256]
    unsigned short* packedW = (unsigned short*)d_ws;
    float* sumPart = (float*)((char*)d_ws + 4 * SEG_ELEMS * sizeof(unsigned short));
    float* sqPart  = sumPart + (size_t)NBLK * 128;
    float* mv      = sqPart + (size_t)NBLK * 128;

    hipLaunchKernelGGL(gdc_pack, dim3((4*9*8*64 + 255)/256), dim3(256), 0, stream,
                       W1, W2, W3, W4, Wself, packedW);
    hipLaunchKernelGGL(gdc_mfma, dim3(NBLK), dim3(512), 0, stream,
                       atom, bond, a1, b1, a2, b2, a3, b3, a4, b4,
                       packedW, out, sumPart, sqPart);
    hipLaunchKernelGGL(gdc_stats, dim3(128), dim3(256), 0, stream,
                       sumPart, sqPart, mv);
    hipLaunchKernelGGL(gdc_norm, dim3(2048), dim3(256), 0, stream, out, mv);
}

// Round 14
// 329.427 us; speedup vs baseline: 1.7413x; 1.0030x over previous
//
#include <hip/hip_runtime.h>
#include <hip/hip_bf16.h>
#include <math.h>

#define N_ATOMS 500000
#define EPS 1e-5f
#define LDA 296   // bf16 elems per A row: 288 + 8 pad

// blocks per degree segment (1024 blocks), proportional to gather volume n_d*(d+1)
#define NB1 55
#define NB2 249
#define NB3 443
#define NB4 277
#define NBLK 1024

#define SEG_ELEMS 36864   // 288*128 bf16 per packed weight segment

typedef __attribute__((ext_vector_type(8))) short short8;
typedef __attribute__((ext_vector_type(4))) float floatx4;

__device__ __forceinline__ unsigned short f2bf(float f) {
    unsigned int x = __float_as_uint(f);
    x += 0x7FFF + ((x >> 16) & 1);          // round-to-nearest-even
    return (unsigned short)(x >> 16);
}

__device__ __forceinline__ float4 add4(float4 a, float4 b) {
    return make_float4(a.x + b.x, a.y + b.y, a.z + b.z, a.w + b.w);
}

__device__ __forceinline__ void st_bf4(unsigned short* p, float4 v) {
    ushort4 u;
    u.x = f2bf(v.x); u.y = f2bf(v.y); u.z = f2bf(v.z); u.w = f2bf(v.w);
    *reinterpret_cast<ushort4*>(p) = u;     // ds_write_b64
}

// ---------------------------------------------------------------------------
// Pack weights into MFMA B-fragment layout, bf16.
// packed[d]: (ks 0..8, nt 0..7, lane 0..63) -> short8; col = nt*16+(lane&15),
// k = ks*32 + (lane>>4)*8 + j; k<144 -> W_d rows, k<272 -> W_self, else 0.
// ---------------------------------------------------------------------------
__global__ __launch_bounds__(256) void gdc_pack(
    const float* __restrict__ W1, const float* __restrict__ W2,
    const float* __restrict__ W3, const float* __restrict__ W4,
    const float* __restrict__ Wself, unsigned short* __restrict__ packed)
{
    const int t = blockIdx.x * 256 + threadIdx.x;
    if (t >= 4 * 9 * 8 * 64) return;
    const int d    = t / 4608;
    const int r    = t % 4608;
    const int ks   = r / 512;
    const int nt   = (r % 512) / 64;
    const int lane = r % 64;
    const float* Wd = (d == 0) ? W1 : (d == 1) ? W2 : (d == 2) ? W3 : W4;
    const int col = nt * 16 + (lane & 15);
    short8 v;
    #pragma unroll
    for (int j = 0; j < 8; ++j) {
        const int k = ks * 32 + ((lane >> 4) << 3) + j;
        float w = 0.f;
        if (k < 144)      w = Wd[k * 128 + col];
        else if (k < 272) w = Wself[(k - 144) * 128 + col];
        v[j] = (short)f2bf(w);
    }
    *reinterpret_cast<short8*>(packed + (size_t)d * SEG_ELEMS
                               + ((size_t)(ks * 8 + nt) * 64 + lane) * 8) = v;
}

// ---------------------------------------------------------------------------
// Pipelined block loop: 8 waves, wave wv owns cols [16wv,16wv+16).
// Raw gathered rows live in DEDICATED registers ra[DEG+1][2] across the
// iteration: all row loads issue back-to-back (parallel, one latency),
// adds+bf16 convert happen at the NEXT commit (write-late), overlapped by
// a full tile of MFMA+scatter. Double-buffered A; one barrier per tile.
// ---------------------------------------------------------------------------
template <int DEG>
__device__ __forceinline__ void block_loop(
    const float* __restrict__ atom, const float* __restrict__ bond,
    const int* __restrict__ aidx, const int* __restrict__ bidx,
    const unsigned short* __restrict__ pw,
    float* __restrict__ out,
    unsigned short* __restrict__ A, int* __restrict__ own_lds,
    int n, int lb, int nb, int tid, int lane, int wv)
{
    const int m    = tid >> 4;           // node row 0..31
    const int q16  = tid & 15;           // 8-float k-slice
    const int ccol = lane & 15;
    const int crow = lane >> 4;
    const int nbase = wv * 16;

    // ---- B fragments once per kernel (9 x short8 = 36 VGPR) ----
    short8 bfr[9];
    #pragma unroll
    for (int ks = 0; ks < 9; ++ks)
        bfr[ks] = ((const short8*)pw)[(ks * 8 + wv) * 64 + lane];

    float psum = 0.f, psq = 0.f;
    const int tiles = (n + 31) >> 5;
    const int nmax  = n - 1;

    float4 ra[DEG + 1][2];               // raw gathered atom rows (parallel)
    float2 rb[DEG];                      // raw bond slices
    int own_r;
    int ni[DEG + 1];

    // ---- prologue: issue tile lb's loads; prefetch idx row of lb+nb ----
    {
        const int i = min((lb << 5) + m, nmax);
        const int* ar = aidx + (size_t)i * (DEG + 1);
        #pragma unroll
        for (int j = 0; j <= DEG; ++j) ni[j] = ar[j];
        own_r = ni[0];
        #pragma unroll
        for (int j = 0; j <= DEG; ++j) {
            const float4* pp = (const float4*)(atom + (size_t)ni[j] * 128 + q16 * 8);
            ra[j][0] = pp[0]; ra[j][1] = pp[1];
        }
        if (q16 < 8) {
            const int* br = bidx + (size_t)i * DEG;
            #pragma unroll
            for (int j = 0; j < DEG; ++j)
                rb[j] = *(const float2*)(bond + (size_t)br[j] * 16 + q16 * 2);
        }
        const int t1 = min(lb + nb, tiles - 1);
        const int i1 = min((t1 << 5) + m, nmax);
        const int* ar1 = aidx + (size_t)i1 * (DEG + 1);
        #pragma unroll
        for (int j = 0; j <= DEG; ++j) ni[j] = ar1[j];
    }

    int k = 0;
    for (int t = lb; t < tiles; t += nb, ++k) {
        unsigned short* Ab = A + (k & 1) * (32 * LDA);
        int* ob = own_lds + (k & 1) * 32;

        // ---- commit tile t: sums from ra/rb -> LDS (vmcnt wait lands here) ----
        {
            unsigned short* rowp = Ab + m * LDA;
            st_bf4(rowp + 144 + q16 * 8 + 0, ra[0][0]);
            st_bf4(rowp + 144 + q16 * 8 + 4, ra[0][1]);
            float4 s0 = ra[0][0], s1 = ra[0][1];
            #pragma unroll
            for (int j = 1; j <= DEG; ++j) {
                s0 = add4(s0, ra[j][0]); s1 = add4(s1, ra[j][1]);
            }
            st_bf4(rowp + q16 * 8 + 0, s0);
            st_bf4(rowp + q16 * 8 + 4, s1);
            if (q16 < 8) {
                float bx = rb[0].x, by = rb[0].y;
                #pragma unroll
                for (int j = 1; j < DEG; ++j) { bx += rb[j].x; by += rb[j].y; }
                rowp[128 + q16 * 2]     = f2bf(bx);
                rowp[128 + q16 * 2 + 1] = f2bf(by);
            }
            if (q16 == 0) ob[m] = own_r;
        }
        __syncthreads();

        // ---- issue ALL of tile t+nb's loads (no interleaved adds) ----
        if (t + nb < tiles) {
            const int i = min(((t + nb) << 5) + m, nmax);
            own_r = ni[0];
            #pragma unroll
            for (int j = 0; j <= DEG; ++j) {
                const float4* pp = (const float4*)(atom + (size_t)ni[j] * 128 + q16 * 8);
                ra[j][0] = pp[0]; ra[j][1] = pp[1];
            }
            if (q16 < 8) {
                const int* br = bidx + (size_t)i * DEG;
                #pragma unroll
                for (int j = 0; j < DEG; ++j)
                    rb[j] = *(const float2*)(bond + (size_t)br[j] * 16 + q16 * 2);
            }
            const int t2 = min(t + 2 * nb, tiles - 1);
            const int i2 = min((t2 << 5) + m, nmax);
            const int* ar2 = aidx + (size_t)i2 * (DEG + 1);
            #pragma unroll
            for (int j = 0; j <= DEG; ++j) ni[j] = ar2[j];
        }

        // ---- MFMA tile t (loads above stay in flight under this) ----
        floatx4 acc0 = (floatx4){0.f, 0.f, 0.f, 0.f};
        floatx4 acc1 = (floatx4){0.f, 0.f, 0.f, 0.f};
        #pragma unroll
        for (int ks = 0; ks < 9; ++ks) {
            const short8 af0 = *(const short8*)&Ab[ccol * LDA + ks * 32 + (crow << 3)];
            const short8 af1 = *(const short8*)&Ab[(16 + ccol) * LDA + ks * 32 + (crow << 3)];
            acc0 = __builtin_amdgcn_mfma_f32_16x16x32_bf16(af0, bfr[ks], acc0, 0, 0, 0);
            acc1 = __builtin_amdgcn_mfma_f32_16x16x32_bf16(af1, bfr[ks], acc1, 0, 0, 0);
        }

        // ---- scatter + BN partials ----
        const int i0 = t << 5;
        const int4 o0 = *reinterpret_cast<const int4*>(&ob[crow * 4]);
        const int4 o1 = *reinterpret_cast<const int4*>(&ob[16 + crow * 4]);
        const int owns0[4] = {o0.x, o0.y, o0.z, o0.w};
        const int owns1[4] = {o1.x, o1.y, o1.z, o1.w};
        #pragma unroll
        for (int rr = 0; rr < 4; ++rr) {
            const int row = crow * 4 + rr;
            if (i0 + row < n) {
                const float v = acc0[rr];
                out[(size_t)owns0[rr] * 128 + nbase + ccol] = v;
                psum += v; psq += v * v;
            }
            if (i0 + 16 + row < n) {
                const float v = acc1[rr];
                out[(size_t)owns1[rr] * 128 + nbase + ccol] = v;
                psum += v; psq += v * v;
            }
        }
    }

    __syncthreads();   // all waves done with LDS before aliasing it

    // ---- per-block channel partials: waves own disjoint 16-col slices ----
    float* redS = reinterpret_cast<float*>(A);          // [128]
    float* redQ = redS + 128;                           // [128]
    {
        float s = psum, q = psq;
        s += __shfl_xor(s, 16, 64); s += __shfl_xor(s, 32, 64);
        q += __shfl_xor(q, 16, 64); q += __shfl_xor(q, 32, 64);
        if (lane < 16) {
            redS[nbase + lane] = s;
            redQ[nbase + lane] = q;
        }
    }
}

// ---------------------------------------------------------------------------
// Fused kernel: 512 threads = 8 waves; 38.1 KB LDS (double-buffered A).
// ---------------------------------------------------------------------------
__global__ __launch_bounds__(512, 4) void gdc_mfma(
    const float* __restrict__ atom, const float* __restrict__ bond,
    const int* __restrict__ a1, const int* __restrict__ b1,
    const int* __restrict__ a2, const int* __restrict__ b2,
    const int* __restrict__ a3, const int* __restrict__ b3,
    const int* __restrict__ a4, const int* __restrict__ b4,
    const unsigned short* __restrict__ packedW,
    float* __restrict__ out,
    float* __restrict__ sumPart, float* __restrict__ sqPart)
{
    __shared__ __align__(16) unsigned short A[2 * 32 * LDA];   // 37888 B
    __shared__ __align__(16) int own_lds[2 * 32];

    const int tid  = threadIdx.x;
    const int wv   = tid >> 6;
    const int lane = tid & 63;
    const int blk  = blockIdx.x;

    int n, lb, nb, deg;
    const int* aidx; const int* bidx;
    if (blk < NB1)                 { deg = 1; n =  50000; lb = blk;                 nb = NB1; aidx = a1; bidx = b1; }
    else if (blk < NB1+NB2)        { deg = 2; n = 150000; lb = blk-NB1;             nb = NB2; aidx = a2; bidx = b2; }
    else if (blk < NB1+NB2+NB3)    { deg = 3; n = 200000; lb = blk-(NB1+NB2);       nb = NB3; aidx = a3; bidx = b3; }
    else                           { deg = 4; n = 100000; lb = blk-(NB1+NB2+NB3);   nb = NB4; aidx = a4; bidx = b4; }

    const unsigned short* pw = packedW + (size_t)(deg - 1) * SEG_ELEMS;

    // zero K-pad cols 272..287 of both buffers once
    {
        const int mm = tid >> 4, qq = tid & 15;
        if (qq >= 8) {
            ushort2 z; z.x = 0; z.y = 0;
            *reinterpret_cast<ushort2*>(&A[mm * LDA + 272 + (qq - 8) * 2]) = z;
            *reinterpret_cast<ushort2*>(&A[32 * LDA + mm * LDA + 272 + (qq - 8) * 2]) = z;
        }
    }
    __syncthreads();

    switch (deg) {
    case 1:  block_loop<1>(atom, bond, aidx, bidx, pw, out, A, own_lds, n, lb, nb, tid, lane, wv); break;
    case 2:  block_loop<2>(atom, bond, aidx, bidx, pw, out, A, own_lds, n, lb, nb, tid, lane, wv); break;
    case 3:  block_loop<3>(atom, bond, aidx, bidx, pw, out, A, own_lds, n, lb, nb, tid, lane, wv); break;
    default: block_loop<4>(atom, bond, aidx, bidx, pw, out, A, own_lds, n, lb, nb, tid, lane, wv); break;
    }

    __syncthreads();
    const float* redS = reinterpret_cast<const float*>(A);
    if (tid < 128)      sumPart[(size_t)blk * 128 + tid] = redS[tid];
    else if (tid < 256) sqPart[(size_t)blk * 128 + (tid - 128)] = redS[tid];
}

// ---------------------------------------------------------------------------
// Reduce NBLK partials per channel -> mean, invstd (deterministic).
// ---------------------------------------------------------------------------
__global__ void gdc_stats(const float* __restrict__ sumPart,
                          const float* __restrict__ sqPart,
                          float* __restrict__ mv)
{
    const int c = blockIdx.x;
    const int j = threadIdx.x;
    __shared__ float rs[256], rq[256];
    float s = 0.f, q = 0.f;
    for (int b = j; b < NBLK; b += 256) {
        s += sumPart[(size_t)b * 128 + c];
        q += sqPart[(size_t)b * 128 + c];
    }
    rs[j] = s; rq[j] = q;
    __syncthreads();
    for (int off = 128; off > 0; off >>= 1) {
        if (j < off) { rs[j] += rs[j + off]; rq[j] += rq[j + off]; }
        __syncthreads();
    }
    if (j == 0) {
        const float mean = rs[0] / (float)N_ATOMS;
        const float var  = rq[0] / (float)N_ATOMS - mean * mean;
        mv[c]       = mean;
        mv[128 + c] = rsqrtf(var + EPS);
    }
}

// ---------------------------------------------------------------------------
// In-place normalize + ReLU. Native-vector float4 non-temporal load/store.
// ---------------------------------------------------------------------------
__global__ __launch_bounds__(256) void gdc_norm(float* __restrict__ out,
                                                const float* __restrict__ mv)
{
    const size_t total4 = (size_t)N_ATOMS * 128 / 4;
    size_t idx = (size_t)blockIdx.x * 256 + threadIdx.x;
    const int c = (int)((idx * 4) & 127);
    const float4 m  = *(const float4*)(mv + c);
    const float4 iv = *(const float4*)(mv + 128 + c);
    const size_t stride = (size_t)gridDim.x * 256;
    for (; idx < total4; idx += stride) {
        floatx4 v = __builtin_nontemporal_load(((const floatx4*)out) + idx);
        v[0] = fmaxf(0.f, (v[0] - m.x) * iv.x);
        v[1] = fmaxf(0.f, (v[1] - m.y) * iv.y);
        v[2] = fmaxf(0.f, (v[2] - m.z) * iv.z);
        v[3] = fmaxf(0.f, (v[3] - m.w) * iv.w);
        __builtin_nontemporal_store(v, ((floatx4*)out) + idx);
    }
}

extern "C" void kernel_launch(void* const* d_in, const int* in_sizes, int n_in,
                              void* d_out, int out_size, void* d_ws, size_t ws_size,
                              hipStream_t stream) {
    const float* atom  = (const float*)d_in[0];
    const float* bond  = (const float*)d_in[1];
    const int*   a1    = (const int*)d_in[2];
    const int*   b1    = (const int*)d_in[3];
    const int*   a2    = (const int*)d_in[4];
    const int*   b2    = (const int*)d_in[5];
    const int*   a3    = (const int*)d_in[6];
    const int*   b3    = (const int*)d_in[7];
    const int*   a4    = (const int*)d_in[8];
    const int*   b4    = (const int*)d_in[9];
    const float* Wself = (const float*)d_in[10];
    const float* W1    = (const float*)d_in[11];
    const float* W2    = (const float*)d_in[12];
    const float* W3    = (const float*)d_in[13];
    const float* W4    = (const float*)d_in[14];
    // bias cancels under BatchNorm (shift-invariance; verified R5/R6) -> unused
    float* out = (float*)d_out;

    // ws layout: packedW (294912 B) | sumPart[NBLK*128] | sqPart[NBLK*128] | mv[256]
    unsigned short* packedW = (unsigned short*)d_ws;
    float* sumPart = (float*)((char*)d_ws + 4 * SEG_ELEMS * sizeof(unsigned short));
    float* sqPart  = sumPart + (size_t)NBLK * 128;
    float* mv      = sqPart + (size_t)NBLK * 128;

    hipLaunchKernelGGL(gdc_pack, dim3((4*9*8*64 + 255)/256), dim3(256), 0, stream,
                       W1, W2, W3, W4, Wself, packedW);
    hipLaunchKernelGGL(gdc_mfma, dim3(NBLK), dim3(512), 0, stream,
                       atom, bond, a1, b1, a2, b2, a3, b3, a4, b4,
                       packedW, out, sumPart, sqPart);
    hipLaunchKernelGGL(gdc_stats, dim3(128), dim3(256), 0, stream,
                       sumPart, sqPart, mv);
    hipLaunchKernelGGL(gdc_norm, dim3(2048), dim3(256), 0, stream, out, mv);
}